// Round 10
// baseline (843.424 us; speedup 1.0000x reference)
//
#include <hip/hip_runtime.h>
#include <hip/hip_bf16.h>

typedef __bf16 bf16;
typedef __bf16 bf16x8 __attribute__((ext_vector_type(8)));
typedef float f32x4 __attribute__((ext_vector_type(4)));
typedef float floatv4 __attribute__((ext_vector_type(4)));

#define LOG2E 1.4426950408889634f
#define QK_SCALE2 (0.17677669529663687f * 1.4426950408889634f)

// ---- swizzled LDS addressing -------------------------------------------------
// q tiles: [50][32] bf16/head (row 49 = P-stage scratch); k tiles: [49][32].
__device__ __forceinline__ bf16* qk_ptr(bf16* base, int row, int col) {
    return base + row * 32 + ((((col >> 3) ^ ((row >> 1) & 3)) << 3)) + (col & 7);
}
// vt tile: [32][64] bf16 per head. chunk' = chunk ^ (row&7).
__device__ __forceinline__ bf16* vt_ptr(bf16* base, int row, int col) {
    return base + row * 64 + ((((col >> 3) ^ (row & 7)) << 3)) + (col & 7);
}
// 192-col tiles (x staging, ao): 24 16B-chunks/row, chunk' = chunk ^ (row&7).
__device__ __forceinline__ bf16* t192_ptr(bf16* base, int row, int col) {
    return base + row * 192 + ((((col >> 3) ^ (row & 7)) << 3)) + (col & 7);
}

// ------------- prep: weight bf16 convert + rpb expand + combo table -----------
__global__ void wmsa_prep(const float* __restrict__ qkv_w,
                          const float* __restrict__ out_w,
                          const float* __restrict__ rpb_table,
                          const float* __restrict__ mask,
                          bf16* __restrict__ qkv_wb,
                          bf16* __restrict__ out_wb,
                          float* __restrict__ rpbx,
                          float* __restrict__ combo,
                          int build_combo) {
    int t = blockIdx.x * 256 + threadIdx.x;
    if (t < 110592) qkv_wb[t] = (bf16)qkv_w[t];
    if (t < 36864)  out_wb[t] = (bf16)out_w[t];
    if (t < 14406) {
        int h = t / 2401, ij = t % 2401, i = ij / 49, j = ij % 49;
        int ri = (i / 7 - j / 7 + 6) * 13 + (i % 7 - j % 7 + 6);
        rpbx[t] = rpb_table[ri * 6 + h];
    }
    if (build_combo && t < 64 * 6 * 64 * 64) {
        int j = t & 63, i = (t >> 6) & 63, r = t >> 12;
        int h = r % 6, w = r / 6;
        float v = -1e30f;
        if (i < 49 && j < 49) {
            int ri = (i / 7 - j / 7 + 6) * 13 + (i % 7 - j % 7 + 6);
            v = (rpb_table[ri * 6 + h] + mask[w * 2401 + i * 49 + j]) * LOG2E;
        }
        combo[t] = v;
    }
}

// ======= fused kernel: one window per 384-thread block, 2 blocks/CU ==========
// LDS 81408 B -> 2 blocks per 160 KiB CU.  __launch_bounds__(384,3): 170-reg cap.
template <bool USE_COMBO>
__global__ __launch_bounds__(384, 3) void wmsa_fused(
    const float* __restrict__ x, const float* __restrict__ mask,
    const float* __restrict__ qkv_b, const float* __restrict__ out_b,
    const bf16* __restrict__ qkv_wb, const bf16* __restrict__ out_wb,
    const float* __restrict__ rpbx, const float* __restrict__ combo,
    float* __restrict__ out)
{
    // elems: s_x 9408 | s_q 6x1600=9600 | s_k 6x1568=9408 | s_vt 6x2048=12288
    __shared__ __align__(16) bf16 s_lds[40704];   // 81408 B
    bf16* s_x  = s_lds;
    bf16* s_q  = s_lds + 9408;
    bf16* s_k  = s_lds + 19008;
    bf16* s_vt = s_lds + 28416;
    bf16* s_ao = s_lds + 9408;     // [64][192] overlays q+k after post-PV barrier

    const int b    = blockIdx.x;
    const int tid  = threadIdx.x;
    const int wv   = tid >> 6;      // 0..5
    const int lane = tid & 63;
    const int lo   = lane & 15;
    const int hi   = lane >> 4;     // 0..3

    const float* xw    = x + (size_t)b * 9408;
    const int    obase = wv * 96;   // 96 qkv output cols per wave
    const int    sec   = wv >> 1;   // 0=q 1=k 2=v (uniform per wave)

    // ============ Phase 0: stage x (fp32 -> bf16) into LDS [49][192] ==========
#pragma unroll
    for (int q2 = 0; q2 < 4; ++q2) {
        const int gc = q2 * 384 + tid;            // 0..1175 chunks of 16B
        if (gc < 1176) {
            const int rs = gc / 24, cc = gc % 24;
            const float* p = xw + rs * 192 + cc * 8;
            floatv4 f0 = *(const floatv4*)p;
            floatv4 f1 = *(const floatv4*)(p + 4);
            bf16x8 v;
            v[0]=(bf16)f0[0]; v[1]=(bf16)f0[1]; v[2]=(bf16)f0[2]; v[3]=(bf16)f0[3];
            v[4]=(bf16)f1[0]; v[5]=(bf16)f1[1]; v[6]=(bf16)f1[2]; v[7]=(bf16)f1[3];
            *(bf16x8*)&s_x[(rs * 24 + (cc ^ (rs & 7))) * 8] = v;
        }
    }
    __syncthreads();

    // ============ Phase 1: QKV = x @ qkv_w^T + qkv_b (6 n-tiles per wave) =====
#pragma unroll 1
    for (int mib = 0; mib < 2; ++mib) {
        f32x4 acc[2][6];
#pragma unroll
        for (int mi = 0; mi < 2; ++mi)
#pragma unroll
            for (int nj = 0; nj < 6; ++nj) acc[mi][nj] = (f32x4){0.f, 0.f, 0.f, 0.f};

        const int r0 = mib * 32 + lo;             // <= 47
        const int r1 = min(r0 + 16, 48);          // rows >= 49 read row 48 (discarded)

        auto loadB = [&](bf16x8* dst, int kk) {
#pragma unroll
            for (int nj = 0; nj < 6; ++nj)
                dst[nj] = *(const bf16x8*)(qkv_wb + (obase + nj * 16 + lo) * 192 + kk * 32 + hi * 8);
        };

        bf16x8 bc[6], bn[6];
        loadB(bc, 0);
#pragma unroll
        for (int kk = 0; kk < 6; ++kk) {
            if (kk < 5) loadB(bn, kk + 1);
            bf16x8 a0 = *(const bf16x8*)t192_ptr(s_x, r0, kk * 32 + hi * 8);
            bf16x8 a1 = *(const bf16x8*)t192_ptr(s_x, r1, kk * 32 + hi * 8);
#pragma unroll
            for (int nj = 0; nj < 6; ++nj) {
                acc[0][nj] = __builtin_amdgcn_mfma_f32_16x16x32_bf16(a0, bc[nj], acc[0][nj], 0, 0, 0);
                acc[1][nj] = __builtin_amdgcn_mfma_f32_16x16x32_bf16(a1, bc[nj], acc[1][nj], 0, 0, 0);
            }
#pragma unroll
            for (int nj = 0; nj < 6; ++nj) bc[nj] = bn[nj];
        }

        // epilogue: bias + scatter into q / k / v^T LDS tiles (n>=49 dropped)
#pragma unroll
        for (int nj = 0; nj < 6; ++nj) {
            const int o    = obase + nj * 16 + lo;
            const float bs = qkv_b[o];
            const int oc   = o - sec * 192;
            const int hh   = oc >> 5;
            const int dd   = oc & 31;
#pragma unroll
            for (int mi = 0; mi < 2; ++mi)
#pragma unroll
                for (int r = 0; r < 4; ++r) {
                    const int n = mib * 32 + mi * 16 + hi * 4 + r;
                    const float v = acc[mi][nj][r] + bs;
                    if (sec == 0)      { if (n < 49) *qk_ptr(s_q + hh * 1600, n, dd) = (bf16)(v * QK_SCALE2); }
                    else if (sec == 1) { if (n < 49) *qk_ptr(s_k + hh * 1568, n, dd) = (bf16)v; }
                    else               *vt_ptr(s_vt + hh * 2048, dd, n) = (bf16)v;
                }
        }
    }
    __syncthreads();

    // ============ Phase 2: attention, head h = wave, 2 serial 32-row passes ===
    {
        const int h = wv;
        bf16* qb    = s_q + h * 1600;
        bf16* kbase = s_k + h * 1568;

        f32x4 oacc[2][2][2];   // [pass][m][nd] -- all loops unrolled (static idx)
#pragma unroll
        for (int p = 0; p < 2; ++p)
#pragma unroll
            for (int m = 0; m < 2; ++m)
#pragma unroll
                for (int nd = 0; nd < 2; ++nd) oacc[p][m][nd] = (f32x4){0.f,0.f,0.f,0.f};

#pragma unroll
        for (int p = 0; p < 2; ++p) {
            const int rowb = p * 32;

            // combo loads issued first (latency hidden under LDS reads + MFMA)
            f32x4 cv[2][4];
            if (USE_COMBO) {
                const float* cb = combo + (((size_t)(b & 63) * 6 + h) << 12);
#pragma unroll
                for (int mi = 0; mi < 2; ++mi)
#pragma unroll
                    for (int nt = 0; nt < 4; ++nt)
#pragma unroll
                        for (int r = 0; r < 4; ++r)
                            cv[mi][nt][r] = cb[(rowb + mi * 16 + hi * 4 + r) * 64 + nt * 16 + lo];
            }

            bf16x8 qa0 = *(const bf16x8*)qk_ptr(qb, rowb + lo, hi * 8);
            bf16x8 qa1 = *(const bf16x8*)qk_ptr(qb, min(rowb + 16 + lo, 49), hi * 8);
            bf16x8 kb0 = *(const bf16x8*)qk_ptr(kbase,  0 + lo, hi * 8);
            bf16x8 kb1 = *(const bf16x8*)qk_ptr(kbase, 16 + lo, hi * 8);
            bf16x8 kb2 = *(const bf16x8*)qk_ptr(kbase, 32 + lo, hi * 8);
            bf16x8 kb3 = *(const bf16x8*)qk_ptr(kbase, 48, hi * 8);   // j>=49 masked

            f32x4 s[2][4];
#pragma unroll
            for (int mi = 0; mi < 2; ++mi)
#pragma unroll
                for (int nt = 0; nt < 4; ++nt) s[mi][nt] = (f32x4){0.f, 0.f, 0.f, 0.f};
            s[0][0] = __builtin_amdgcn_mfma_f32_16x16x32_bf16(qa0, kb0, s[0][0], 0, 0, 0);
            s[0][1] = __builtin_amdgcn_mfma_f32_16x16x32_bf16(qa0, kb1, s[0][1], 0, 0, 0);
            s[0][2] = __builtin_amdgcn_mfma_f32_16x16x32_bf16(qa0, kb2, s[0][2], 0, 0, 0);
            s[0][3] = __builtin_amdgcn_mfma_f32_16x16x32_bf16(qa0, kb3, s[0][3], 0, 0, 0);
            s[1][0] = __builtin_amdgcn_mfma_f32_16x16x32_bf16(qa1, kb0, s[1][0], 0, 0, 0);
            s[1][1] = __builtin_amdgcn_mfma_f32_16x16x32_bf16(qa1, kb1, s[1][1], 0, 0, 0);
            s[1][2] = __builtin_amdgcn_mfma_f32_16x16x32_bf16(qa1, kb2, s[1][2], 0, 0, 0);
            s[1][3] = __builtin_amdgcn_mfma_f32_16x16x32_bf16(qa1, kb3, s[1][3], 0, 0, 0);

            if (USE_COMBO) {
#pragma unroll
                for (int mi = 0; mi < 2; ++mi)
#pragma unroll
                    for (int nt = 0; nt < 4; ++nt) s[mi][nt] += cv[mi][nt];
            } else {
                const float* mk = mask + (size_t)(b & 63) * 2401;
                const float* rb = rpbx + h * 2401;
#pragma unroll
                for (int nt = 0; nt < 4; ++nt) {
                    const int j = nt * 16 + lo;
#pragma unroll
                    for (int mi = 0; mi < 2; ++mi)
#pragma unroll
                        for (int r = 0; r < 4; ++r) {
                            const int i = rowb + mi * 16 + hi * 4 + r;
                            float sv = s[mi][nt][r];
                            if (j >= 49 || i >= 49) sv = -1e30f;
                            else sv += (rb[i * 49 + j] + mk[i * 49 + j]) * LOG2E;
                            s[mi][nt][r] = sv;
                        }
                }
            }

            // softmax over j (exp2 domain)
#pragma unroll
            for (int mi = 0; mi < 2; ++mi)
#pragma unroll
                for (int r = 0; r < 4; ++r) {
                    float m = fmaxf(fmaxf(s[mi][0][r], s[mi][1][r]),
                                    fmaxf(s[mi][2][r], s[mi][3][r]));
                    m = fmaxf(m, __shfl_xor(m, 1));
                    m = fmaxf(m, __shfl_xor(m, 2));
                    m = fmaxf(m, __shfl_xor(m, 4));
                    m = fmaxf(m, __shfl_xor(m, 8));
                    float sum = 0.f;
#pragma unroll
                    for (int nt = 0; nt < 4; ++nt) {
                        float pv = exp2f(s[mi][nt][r] - m);
                        s[mi][nt][r] = pv;
                        sum += pv;
                    }
                    sum += __shfl_xor(sum, 1);
                    sum += __shfl_xor(sum, 2);
                    sum += __shfl_xor(sum, 4);
                    sum += __shfl_xor(sum, 8);
                    const float inv = 1.0f / sum;
#pragma unroll
                    for (int nt = 0; nt < 4; ++nt) s[mi][nt][r] *= inv;
                }

            // PV: P staged into this pass's own q rows (row 49 = garbage dump)
#pragma unroll
            for (int kk = 0; kk < 2; ++kk) {
#pragma unroll
                for (int mi = 0; mi < 2; ++mi)
#pragma unroll
                    for (int c = 0; c < 2; ++c) {
                        const int nt = kk * 2 + c;
#pragma unroll
                        for (int r = 0; r < 4; ++r)
                            *qk_ptr(qb, min(rowb + mi * 16 + hi * 4 + r, 49), c * 16 + lo) =
                                (bf16)s[mi][nt][r];
                    }
                bf16x8 pa0 = *(const bf16x8*)qk_ptr(qb, rowb + lo, hi * 8);
                bf16x8 pa1 = *(const bf16x8*)qk_ptr(qb, min(rowb + 16 + lo, 49), hi * 8);
                bf16x8 vb0 = *(const bf16x8*)vt_ptr(s_vt + h * 2048,  0 + lo, kk * 32 + hi * 8);
                bf16x8 vb1 = *(const bf16x8*)vt_ptr(s_vt + h * 2048, 16 + lo, kk * 32 + hi * 8);
                oacc[p][0][0] = __builtin_amdgcn_mfma_f32_16x16x32_bf16(pa0, vb0, oacc[p][0][0], 0, 0, 0);
                oacc[p][1][0] = __builtin_amdgcn_mfma_f32_16x16x32_bf16(pa1, vb0, oacc[p][1][0], 0, 0, 0);
                oacc[p][0][1] = __builtin_amdgcn_mfma_f32_16x16x32_bf16(pa0, vb1, oacc[p][0][1], 0, 0, 0);
                oacc[p][1][1] = __builtin_amdgcn_mfma_f32_16x16x32_bf16(pa1, vb1, oacc[p][1][1], 0, 0, 0);
            }
        }
        __syncthreads();   // all q/k/P reads done -> ao overlay of q+k safe

        // scatter head output into ao [64][192]
#pragma unroll
        for (int p = 0; p < 2; ++p)
#pragma unroll
            for (int r = 0; r < 4; ++r) {
                const int n0 = p * 32 + hi * 4 + r;
                const int n1 = n0 + 16;
                *t192_ptr(s_ao, n0, h * 32 +  0 + lo) = (bf16)oacc[p][0][0][r];
                *t192_ptr(s_ao, n0, h * 32 + 16 + lo) = (bf16)oacc[p][0][1][r];
                *t192_ptr(s_ao, n1, h * 32 +  0 + lo) = (bf16)oacc[p][1][0][r];
                *t192_ptr(s_ao, n1, h * 32 + 16 + lo) = (bf16)oacc[p][1][1][r];
            }
    }
    __syncthreads();

    // ============ Phase 3: out = ao @ out_w^T + out_b (2 col-tiles per wave) ==
    {
        f32x4 facc[2][4];
#pragma unroll
        for (int t2 = 0; t2 < 2; ++t2)
#pragma unroll
            for (int mi = 0; mi < 4; ++mi) facc[t2][mi] = (f32x4){0.f, 0.f, 0.f, 0.f};

        const int o20 = wv * 32 + lo;
        const int o21 = o20 + 16;
        bf16x8 fb0c = *(const bf16x8*)(out_wb + o20 * 192 + hi * 8);
        bf16x8 fb1c = *(const bf16x8*)(out_wb + o21 * 192 + hi * 8);
#pragma unroll
        for (int kk = 0; kk < 6; ++kk) {
            bf16x8 fb0n, fb1n;
            if (kk < 5) {
                fb0n = *(const bf16x8*)(out_wb + o20 * 192 + (kk + 1) * 32 + hi * 8);
                fb1n = *(const bf16x8*)(out_wb + o21 * 192 + (kk + 1) * 32 + hi * 8);
            }
            bf16x8 fa[4];
#pragma unroll
            for (int mi = 0; mi < 4; ++mi)
                fa[mi] = *(const bf16x8*)t192_ptr(s_ao, mi * 16 + lo, kk * 32 + hi * 8);
#pragma unroll
            for (int mi = 0; mi < 4; ++mi) {
                facc[0][mi] = __builtin_amdgcn_mfma_f32_16x16x32_bf16(fa[mi], fb0c, facc[0][mi], 0, 0, 0);
                facc[1][mi] = __builtin_amdgcn_mfma_f32_16x16x32_bf16(fa[mi], fb1c, facc[1][mi], 0, 0, 0);
            }
            fb0c = fb0n; fb1c = fb1n;
        }

        float* ow = out + (size_t)b * 9408;
#pragma unroll
        for (int t2 = 0; t2 < 2; ++t2) {
            const int o2 = wv * 32 + t2 * 16 + lo;
            const float ob = out_b[o2];
#pragma unroll
            for (int mi = 0; mi < 4; ++mi)
#pragma unroll
                for (int r = 0; r < 4; ++r) {
                    const int n = mi * 16 + hi * 4 + r;
                    if (n < 49) ow[n * 192 + o2] = facc[t2][mi][r] + ob;
                }
        }
    }
}

extern "C" void kernel_launch(void* const* d_in, const int* in_sizes, int n_in,
                              void* d_out, int out_size, void* d_ws, size_t ws_size,
                              hipStream_t stream) {
    const float* x      = (const float*)d_in[0];
    const float* mask   = (const float*)d_in[1];
    const float* qkv_w  = (const float*)d_in[2];
    const float* qkv_b  = (const float*)d_in[3];
    const float* out_w  = (const float*)d_in[4];
    const float* out_b  = (const float*)d_in[5];
    const float* rpb    = (const float*)d_in[6];
    float* out          = (float*)d_out;

    char* ws = (char*)d_ws;
    bf16*  qkv_wb = (bf16*)ws;                       // 110592 * 2 = 221184 B
    bf16*  out_wb = (bf16*)(ws + 221184);            //  36864 * 2 =  73728 B
    float* rpbx   = (float*)(ws + 294912);           //  14406 * 4 =  57624 B
    float* combo  = (float*)(ws + 352768);           // 1572864 * 4 = 6291456 B
    const bool use_combo = ws_size >= (size_t)(352768 + 6291456);

    hipLaunchKernelGGL(wmsa_prep, dim3(6144), dim3(256), 0, stream,
                       qkv_w, out_w, rpb, mask, qkv_wb, out_wb, rpbx, combo,
                       use_combo ? 1 : 0);
    if (use_combo)
        hipLaunchKernelGGL(HIP_KERNEL_NAME(wmsa_fused<true>), dim3(4096), dim3(384), 0, stream,
                           x, mask, qkv_b, out_b, qkv_wb, out_wb, rpbx, combo, out);
    else
        hipLaunchKernelGGL(HIP_KERNEL_NAME(wmsa_fused<false>), dim3(4096), dim3(384), 0, stream,
                           x, mask, qkv_b, out_b, qkv_wb, out_wb, rpbx, combo, out);
}

// Round 11
// 540.157 us; speedup vs baseline: 1.5614x; 1.5614x over previous
//
#include <hip/hip_runtime.h>
#include <hip/hip_bf16.h>

typedef __bf16 bf16;
typedef __bf16 bf16x8 __attribute__((ext_vector_type(8)));
typedef float f32x4 __attribute__((ext_vector_type(4)));
typedef float floatv4 __attribute__((ext_vector_type(4)));

#define LOG2E 1.4426950408889634f
// q scale with log2(e) folded in: softmax runs in exp2 domain.
#define QK_SCALE2 (0.17677669529663687f * 1.4426950408889634f)

// ---- swizzled LDS addressing -------------------------------------------------
// q/k tiles: [64][32] bf16 per head (row = 64B = 4 x 16B chunks).
__device__ __forceinline__ bf16* qk_ptr(bf16* base, int row, int col) {
    return base + row * 32 + ((((col >> 3) ^ ((row >> 1) & 3)) << 3)) + (col & 7);
}
// vt tile: [32][64] bf16 per head (row = 128B = 8 chunks). chunk' = chunk ^ (row&7).
__device__ __forceinline__ bf16* vt_ptr(bf16* base, int row, int col) {
    return base + row * 64 + ((((col >> 3) ^ (row & 7)) << 3)) + (col & 7);
}
// 192-col tiles (x staging, ao): 24 16B-chunks/row, chunk' = chunk ^ (row&7).
__device__ __forceinline__ bf16* t192_ptr(bf16* base, int row, int col) {
    return base + row * 192 + ((((col >> 3) ^ (row & 7)) << 3)) + (col & 7);
}

// ------------- prep: weight bf16 convert + rpb expand + combo table -----------
// combo[w][h][i][j] = (rpb[h][i][j] + mask[w][i][j]) * LOG2E, -1e30 padded
__global__ void wmsa_prep(const float* __restrict__ qkv_w,
                          const float* __restrict__ out_w,
                          const float* __restrict__ rpb_table,
                          const float* __restrict__ mask,
                          bf16* __restrict__ qkv_wb,
                          bf16* __restrict__ out_wb,
                          float* __restrict__ rpbx,
                          float* __restrict__ combo,
                          int build_combo) {
    int t = blockIdx.x * 256 + threadIdx.x;
    if (t < 110592) qkv_wb[t] = (bf16)qkv_w[t];
    if (t < 36864)  out_wb[t] = (bf16)out_w[t];
    if (t < 14406) {
        int h = t / 2401, ij = t % 2401, i = ij / 49, j = ij % 49;
        int ri = (i / 7 - j / 7 + 6) * 13 + (i % 7 - j % 7 + 6);
        rpbx[t] = rpb_table[ri * 6 + h];
    }
    if (build_combo && t < 64 * 6 * 64 * 64) {
        int j = t & 63, i = (t >> 6) & 63, r = t >> 12;
        int h = r % 6, w = r / 6;
        float v = -1e30f;
        if (i < 49 && j < 49) {
            int ri = (i / 7 - j / 7 + 6) * 13 + (i % 7 - j % 7 + 6);
            v = (rpb_table[ri * 6 + h] + mask[w * 2401 + i * 49 + j]) * LOG2E;
        }
        combo[t] = v;
    }
}

// ======= persistent fused kernel: 1 block/CU, 16 windows per block ============
#define WIN_PER_BLK 16

template <bool USE_COMBO>
__global__ __launch_bounds__(768, 3) void wmsa_fused(
    const float* __restrict__ x, const float* __restrict__ mask,
    const float* __restrict__ qkv_b, const float* __restrict__ out_b,
    const bf16* __restrict__ qkv_wb, const bf16* __restrict__ out_wb,
    const float* __restrict__ rpbx, const float* __restrict__ combo,
    float* __restrict__ out)
{
    __shared__ __align__(16) bf16 s_x[2][12288];   // x window bf16 [64][192] swz, dbuf
    __shared__ __align__(16) bf16 s_qp[6][2048];   // q, then P (per head)
    __shared__ __align__(16) bf16 s_kao[12288];    // k (per head), then ao[64][192]
    __shared__ __align__(16) bf16 s_vt[6][2048];   // v^T

    const int tid  = threadIdx.x;
    const int wv   = tid >> 6;      // 0..11
    const int lane = tid & 63;
    const int lo   = lane & 15;
    const int hi   = lane >> 4;     // 0..3

    const int obase = wv * 48;      // 48 qkv output cols per wave
    const int sec   = wv >> 2;      // 0=q 1=k 2=v (uniform per wave)
    const int ah    = wv >> 1;      // attention head 0..5
    const int arow  = (wv & 1) * 32;

    // per-thread staging geometry (constant across iterations)
    const int pr0 = tid / 24,         pcc0 = tid % 24;         // chunk tid
    const int pr1 = (tid + 768) / 24, pcc1 = (tid + 768) % 24; // chunk tid+768

    const int bbase = blockIdx.x * WIN_PER_BLK;

    // ============ initial stage: window bbase -> s_x[0] =======================
    {
        const float* xw = x + (size_t)bbase * 9408;
        const float* p0 = xw + pr0 * 192 + pcc0 * 8;
        floatv4 f0 = *(const floatv4*)p0;
        floatv4 f1 = *(const floatv4*)(p0 + 4);
        bf16x8 v;
        v[0]=(bf16)f0[0]; v[1]=(bf16)f0[1]; v[2]=(bf16)f0[2]; v[3]=(bf16)f0[3];
        v[4]=(bf16)f1[0]; v[5]=(bf16)f1[1]; v[6]=(bf16)f1[2]; v[7]=(bf16)f1[3];
        *(bf16x8*)&s_x[0][(pr0 * 24 + (pcc0 ^ (pr0 & 7))) * 8] = v;

        bf16x8 w = {};
        if (pr1 < 49) {
            const float* p1 = xw + pr1 * 192 + pcc1 * 8;
            floatv4 g0 = *(const floatv4*)p1;
            floatv4 g1 = *(const floatv4*)(p1 + 4);
            w[0]=(bf16)g0[0]; w[1]=(bf16)g0[1]; w[2]=(bf16)g0[2]; w[3]=(bf16)g0[3];
            w[4]=(bf16)g1[0]; w[5]=(bf16)g1[1]; w[6]=(bf16)g1[2]; w[7]=(bf16)g1[3];
        }
        *(bf16x8*)&s_x[0][(pr1 * 24 + (pcc1 ^ (pr1 & 7))) * 8] = w;
    }

#pragma unroll 1
    for (int it = 0; it < WIN_PER_BLK; ++it) {
        const int b = bbase + it;
        bf16* sx = &s_x[it & 1][0];

        // staged x visible; prev iteration's ao reads done -> q/k/vt writable
        __syncthreads();

        // ============ Phase 1: QKV = x @ qkv_w^T + qkv_b ======================
#pragma unroll 1
        for (int mib = 0; mib < 2; ++mib) {
            f32x4 acc[2][3];
#pragma unroll
            for (int mi = 0; mi < 2; ++mi)
#pragma unroll
                for (int nj = 0; nj < 3; ++nj) acc[mi][nj] = (f32x4){0.f, 0.f, 0.f, 0.f};

            const int r0 = mib * 32 + lo;
            const int r1 = r0 + 16;        // rows >= 49 are zeros in s_x

            auto loadB = [&](bf16x8* dst, int kk) {
#pragma unroll
                for (int nj = 0; nj < 3; ++nj)
                    dst[nj] = *(const bf16x8*)(qkv_wb + (obase + nj * 16 + lo) * 192 + kk * 32 + hi * 8);
            };

            bf16x8 b0_[3], b1_[3], b2_[3];
            loadB(b0_, 0);
            loadB(b1_, 1);
#pragma unroll
            for (int kk = 0; kk < 6; ++kk) {
                if (kk < 4) loadB(b2_, kk + 2);
                bf16x8 a0 = *(const bf16x8*)t192_ptr(sx, r0, kk * 32 + hi * 8);
                bf16x8 a1 = *(const bf16x8*)t192_ptr(sx, r1, kk * 32 + hi * 8);
                acc[0][0] = __builtin_amdgcn_mfma_f32_16x16x32_bf16(a0, b0_[0], acc[0][0], 0, 0, 0);
                acc[1][0] = __builtin_amdgcn_mfma_f32_16x16x32_bf16(a1, b0_[0], acc[1][0], 0, 0, 0);
                acc[0][1] = __builtin_amdgcn_mfma_f32_16x16x32_bf16(a0, b0_[1], acc[0][1], 0, 0, 0);
                acc[1][1] = __builtin_amdgcn_mfma_f32_16x16x32_bf16(a1, b0_[1], acc[1][1], 0, 0, 0);
                acc[0][2] = __builtin_amdgcn_mfma_f32_16x16x32_bf16(a0, b0_[2], acc[0][2], 0, 0, 0);
                acc[1][2] = __builtin_amdgcn_mfma_f32_16x16x32_bf16(a1, b0_[2], acc[1][2], 0, 0, 0);
                b0_[0] = b1_[0]; b0_[1] = b1_[1]; b0_[2] = b1_[2];
                b1_[0] = b2_[0]; b1_[1] = b2_[1]; b1_[2] = b2_[2];
            }

            // epilogue: bias + scatter into q / k / v^T LDS tiles
#pragma unroll
            for (int nj = 0; nj < 3; ++nj) {
                const int o    = obase + nj * 16 + lo;
                const float bs = qkv_b[o];
                const int oc   = o - sec * 192;
                const int hh   = oc >> 5;
                const int dd   = oc & 31;
#pragma unroll
                for (int mi = 0; mi < 2; ++mi)
#pragma unroll
                    for (int r = 0; r < 4; ++r) {
                        const int n = mib * 32 + mi * 16 + hi * 4 + r;
                        const float v = acc[mi][nj][r] + bs;
                        if (sec == 0)      *qk_ptr(&s_qp[hh][0], n, dd)      = (bf16)(v * QK_SCALE2);
                        else if (sec == 1) *qk_ptr(s_kao + hh * 2048, n, dd) = (bf16)v;
                        else               *vt_ptr(&s_vt[hh][0], dd, n)      = (bf16)v;
                    }
            }
        }
        __syncthreads();

        // ============ Phase 2: attention. wave = (head ah, 32-row pass) =======
        {
            bf16* qb    = &s_qp[ah][0];
            bf16* kbase = s_kao + ah * 2048;

            // combo loads issued first (latency hidden under LDS reads + MFMA)
            f32x4 cv[2][4];
            if (USE_COMBO) {
                const float* cb = combo + (((size_t)(b & 63) * 6 + ah) << 12);
#pragma unroll
                for (int mi = 0; mi < 2; ++mi)
#pragma unroll
                    for (int nt = 0; nt < 4; ++nt)
#pragma unroll
                        for (int r = 0; r < 4; ++r)
                            cv[mi][nt][r] = cb[(arow + mi * 16 + hi * 4 + r) * 64 + nt * 16 + lo];
            }

            bf16x8 qa0 = *(const bf16x8*)qk_ptr(qb, arow + lo, hi * 8);
            bf16x8 qa1 = *(const bf16x8*)qk_ptr(qb, arow + 16 + lo, hi * 8);
            bf16x8 kb0 = *(const bf16x8*)qk_ptr(kbase,  0 + lo, hi * 8);
            bf16x8 kb1 = *(const bf16x8*)qk_ptr(kbase, 16 + lo, hi * 8);
            bf16x8 kb2 = *(const bf16x8*)qk_ptr(kbase, 32 + lo, hi * 8);
            bf16x8 kb3 = *(const bf16x8*)qk_ptr(kbase, 48 + lo, hi * 8);

            // all q/k fragment reads complete -> P-staging and ao overlay safe
            __syncthreads();

            f32x4 s[2][4];
#pragma unroll
            for (int mi = 0; mi < 2; ++mi)
#pragma unroll
                for (int nt = 0; nt < 4; ++nt) s[mi][nt] = (f32x4){0.f, 0.f, 0.f, 0.f};
            s[0][0] = __builtin_amdgcn_mfma_f32_16x16x32_bf16(qa0, kb0, s[0][0], 0, 0, 0);
            s[0][1] = __builtin_amdgcn_mfma_f32_16x16x32_bf16(qa0, kb1, s[0][1], 0, 0, 0);
            s[0][2] = __builtin_amdgcn_mfma_f32_16x16x32_bf16(qa0, kb2, s[0][2], 0, 0, 0);
            s[0][3] = __builtin_amdgcn_mfma_f32_16x16x32_bf16(qa0, kb3, s[0][3], 0, 0, 0);
            s[1][0] = __builtin_amdgcn_mfma_f32_16x16x32_bf16(qa1, kb0, s[1][0], 0, 0, 0);
            s[1][1] = __builtin_amdgcn_mfma_f32_16x16x32_bf16(qa1, kb1, s[1][1], 0, 0, 0);
            s[1][2] = __builtin_amdgcn_mfma_f32_16x16x32_bf16(qa1, kb2, s[1][2], 0, 0, 0);
            s[1][3] = __builtin_amdgcn_mfma_f32_16x16x32_bf16(qa1, kb3, s[1][3], 0, 0, 0);

            if (USE_COMBO) {
#pragma unroll
                for (int mi = 0; mi < 2; ++mi)
#pragma unroll
                    for (int nt = 0; nt < 4; ++nt) s[mi][nt] += cv[mi][nt];
            } else {
                const float* mk = mask + (size_t)(b & 63) * 2401;
                const float* rb = rpbx + ah * 2401;
#pragma unroll
                for (int nt = 0; nt < 4; ++nt) {
                    const int j = nt * 16 + lo;
#pragma unroll
                    for (int mi = 0; mi < 2; ++mi)
#pragma unroll
                        for (int r = 0; r < 4; ++r) {
                            const int i = arow + mi * 16 + hi * 4 + r;
                            float sv = s[mi][nt][r];
                            if (j >= 49 || i >= 49) sv = -1e30f;
                            else sv += (rb[i * 49 + j] + mk[i * 49 + j]) * LOG2E;
                            s[mi][nt][r] = sv;
                        }
                }
            }

            // softmax over j (exp2 domain; 4 regs x 16 lanes sharing hi)
#pragma unroll
            for (int mi = 0; mi < 2; ++mi)
#pragma unroll
                for (int r = 0; r < 4; ++r) {
                    float m = fmaxf(fmaxf(s[mi][0][r], s[mi][1][r]),
                                    fmaxf(s[mi][2][r], s[mi][3][r]));
                    m = fmaxf(m, __shfl_xor(m, 1));
                    m = fmaxf(m, __shfl_xor(m, 2));
                    m = fmaxf(m, __shfl_xor(m, 4));
                    m = fmaxf(m, __shfl_xor(m, 8));
                    float sum = 0.f;
#pragma unroll
                    for (int nt = 0; nt < 4; ++nt) {
                        float pv = exp2f(s[mi][nt][r] - m);
                        s[mi][nt][r] = pv;
                        sum += pv;
                    }
                    sum += __shfl_xor(sum, 1);
                    sum += __shfl_xor(sum, 2);
                    sum += __shfl_xor(sum, 4);
                    sum += __shfl_xor(sum, 8);
                    const float inv = 1.0f / sum;
#pragma unroll
                    for (int nt = 0; nt < 4; ++nt) s[mi][nt][r] *= inv;
                }

            // PV: rows arow..arow+31; P staged into this pass's own q rows
            f32x4 o00 = (f32x4){0.f,0.f,0.f,0.f}, o01 = (f32x4){0.f,0.f,0.f,0.f};
            f32x4 o10 = (f32x4){0.f,0.f,0.f,0.f}, o11 = (f32x4){0.f,0.f,0.f,0.f};
#pragma unroll
            for (int kk = 0; kk < 2; ++kk) {
#pragma unroll
                for (int mi = 0; mi < 2; ++mi)
#pragma unroll
                    for (int c = 0; c < 2; ++c) {
                        const int nt = kk * 2 + c;
#pragma unroll
                        for (int r = 0; r < 4; ++r)
                            *qk_ptr(qb, arow + mi * 16 + hi * 4 + r, c * 16 + lo) =
                                (bf16)s[mi][nt][r];
                    }
                bf16x8 pa0 = *(const bf16x8*)qk_ptr(qb, arow + lo, hi * 8);
                bf16x8 pa1 = *(const bf16x8*)qk_ptr(qb, arow + 16 + lo, hi * 8);
                bf16x8 vb0 = *(const bf16x8*)vt_ptr(&s_vt[ah][0],  0 + lo, kk * 32 + hi * 8);
                bf16x8 vb1 = *(const bf16x8*)vt_ptr(&s_vt[ah][0], 16 + lo, kk * 32 + hi * 8);
                o00 = __builtin_amdgcn_mfma_f32_16x16x32_bf16(pa0, vb0, o00, 0, 0, 0);
                o10 = __builtin_amdgcn_mfma_f32_16x16x32_bf16(pa1, vb0, o10, 0, 0, 0);
                o01 = __builtin_amdgcn_mfma_f32_16x16x32_bf16(pa0, vb1, o01, 0, 0, 0);
                o11 = __builtin_amdgcn_mfma_f32_16x16x32_bf16(pa1, vb1, o11, 0, 0, 0);
            }

            // scatter head output into ao (overlays k; safe post-barrier)
#pragma unroll
            for (int r = 0; r < 4; ++r) {
                const int n0 = arow + hi * 4 + r;
                const int n1 = n0 + 16;
                *t192_ptr(s_kao, n0, ah * 32 +  0 + lo) = (bf16)o00[r];
                *t192_ptr(s_kao, n0, ah * 32 + 16 + lo) = (bf16)o01[r];
                *t192_ptr(s_kao, n1, ah * 32 +  0 + lo) = (bf16)o10[r];
                *t192_ptr(s_kao, n1, ah * 32 + 16 + lo) = (bf16)o11[r];
            }
        }
        __syncthreads();

        // -------- issue next window's x loads (latency hides under phase 3) ---
        floatv4 pf00, pf01, pf10, pf11;
        const bool do_pf = (it + 1 < WIN_PER_BLK);
        if (do_pf) {
            const float* xn = x + (size_t)(b + 1) * 9408;
            const float* p0 = xn + pr0 * 192 + pcc0 * 8;
            pf00 = *(const floatv4*)p0;
            pf01 = *(const floatv4*)(p0 + 4);
            pf10 = (floatv4){0.f,0.f,0.f,0.f};
            pf11 = (floatv4){0.f,0.f,0.f,0.f};
            if (pr1 < 49) {
                const float* p1 = xn + pr1 * 192 + pcc1 * 8;
                pf10 = *(const floatv4*)p1;
                pf11 = *(const floatv4*)(p1 + 4);
            }
        }

        // ============ Phase 3: out = ao @ out_w^T + out_b (1 col-tile/wave) ===
        {
            const int o2 = wv * 16 + lo;           // 0..191
            f32x4 facc[4];
#pragma unroll
            for (int mi = 0; mi < 4; ++mi) facc[mi] = (f32x4){0.f, 0.f, 0.f, 0.f};

            bf16x8 fbc = *(const bf16x8*)(out_wb + o2 * 192 + hi * 8);
#pragma unroll
            for (int kk = 0; kk < 6; ++kk) {
                bf16x8 fbn;
                if (kk < 5) fbn = *(const bf16x8*)(out_wb + o2 * 192 + (kk + 1) * 32 + hi * 8);
                bf16x8 fa[4];
#pragma unroll
                for (int mi = 0; mi < 4; ++mi)
                    fa[mi] = *(const bf16x8*)t192_ptr(s_kao, mi * 16 + lo, kk * 32 + hi * 8);
#pragma unroll
                for (int mi = 0; mi < 4; ++mi)
                    facc[mi] = __builtin_amdgcn_mfma_f32_16x16x32_bf16(fa[mi], fbc, facc[mi], 0, 0, 0);
                fbc = fbn;
            }

            const float ob = out_b[o2];
            float* ow = out + (size_t)b * 9408;
#pragma unroll
            for (int mi = 0; mi < 4; ++mi)
#pragma unroll
                for (int r = 0; r < 4; ++r) {
                    const int n = mi * 16 + hi * 4 + r;
                    if (n < 49) ow[n * 192 + o2] = facc[mi][r] + ob;
                }
        }

        // -------- convert + write prefetched x into the other buffer ----------
        if (do_pf) {
            bf16* xb = &s_x[(it + 1) & 1][0];
            bf16x8 v;
            v[0]=(bf16)pf00[0]; v[1]=(bf16)pf00[1]; v[2]=(bf16)pf00[2]; v[3]=(bf16)pf00[3];
            v[4]=(bf16)pf01[0]; v[5]=(bf16)pf01[1]; v[6]=(bf16)pf01[2]; v[7]=(bf16)pf01[3];
            *(bf16x8*)&xb[(pr0 * 24 + (pcc0 ^ (pr0 & 7))) * 8] = v;
            bf16x8 w;
            w[0]=(bf16)pf10[0]; w[1]=(bf16)pf10[1]; w[2]=(bf16)pf10[2]; w[3]=(bf16)pf10[3];
            w[4]=(bf16)pf11[0]; w[5]=(bf16)pf11[1]; w[6]=(bf16)pf11[2]; w[7]=(bf16)pf11[3];
            *(bf16x8*)&xb[(pr1 * 24 + (pcc1 ^ (pr1 & 7))) * 8] = w;
        }
        // loop-top __syncthreads() makes staged x visible and guards ao reuse
    }
}

extern "C" void kernel_launch(void* const* d_in, const int* in_sizes, int n_in,
                              void* d_out, int out_size, void* d_ws, size_t ws_size,
                              hipStream_t stream) {
    const float* x      = (const float*)d_in[0];
    const float* mask   = (const float*)d_in[1];
    const float* qkv_w  = (const float*)d_in[2];
    const float* qkv_b  = (const float*)d_in[3];
    const float* out_w  = (const float*)d_in[4];
    const float* out_b  = (const float*)d_in[5];
    const float* rpb    = (const float*)d_in[6];
    float* out          = (float*)d_out;

    char* ws = (char*)d_ws;
    bf16*  qkv_wb = (bf16*)ws;                       // 110592 * 2 = 221184 B
    bf16*  out_wb = (bf16*)(ws + 221184);            //  36864 * 2 =  73728 B
    float* rpbx   = (float*)(ws + 294912);           //  14406 * 4 =  57624 B
    float* combo  = (float*)(ws + 352768);           // 1572864 * 4 = 6291456 B
    const bool use_combo = ws_size >= (size_t)(352768 + 6291456);

    hipLaunchKernelGGL(wmsa_prep, dim3(6144), dim3(256), 0, stream,
                       qkv_w, out_w, rpb, mask, qkv_wb, out_wb, rpbx, combo,
                       use_combo ? 1 : 0);
    if (use_combo)
        hipLaunchKernelGGL(HIP_KERNEL_NAME(wmsa_fused<true>), dim3(256), dim3(768), 0, stream,
                           x, mask, qkv_b, out_b, qkv_wb, out_wb, rpbx, combo, out);
    else
        hipLaunchKernelGGL(HIP_KERNEL_NAME(wmsa_fused<false>), dim3(256), dim3(768), 0, stream,
                           x, mask, qkv_b, out_b, qkv_wb, out_wb, rpbx, combo, out);
}

// Round 12
// 341.535 us; speedup vs baseline: 2.4695x; 1.5816x over previous
//
#include <hip/hip_runtime.h>
#include <hip/hip_bf16.h>

typedef __bf16 bf16;
typedef __bf16 bf16x8 __attribute__((ext_vector_type(8)));
typedef float f32x4 __attribute__((ext_vector_type(4)));
typedef float floatv4 __attribute__((ext_vector_type(4)));

#define LOG2E 1.4426950408889634f
// q scale with log2(e) folded in: softmax runs in exp2 domain.
#define QK_SCALE2 (0.17677669529663687f * 1.4426950408889634f)

// ---- swizzled LDS addressing -------------------------------------------------
// q/k tiles: [64][32] bf16 per head (row = 64B = 4 x 16B chunks).
__device__ __forceinline__ bf16* qk_ptr(bf16* base, int row, int col) {
    return base + row * 32 + ((((col >> 3) ^ ((row >> 1) & 3)) << 3)) + (col & 7);
}
// vt tile: [32][64] bf16 per head (row = 128B = 8 chunks). chunk' = chunk ^ (row&7).
__device__ __forceinline__ bf16* vt_ptr(bf16* base, int row, int col) {
    return base + row * 64 + ((((col >> 3) ^ (row & 7)) << 3)) + (col & 7);
}
// 192-col tiles (x staging, ao): 24 16B-chunks/row, chunk' = chunk ^ (row&7).
__device__ __forceinline__ bf16* t192_ptr(bf16* base, int row, int col) {
    return base + row * 192 + ((((col >> 3) ^ (row & 7)) << 3)) + (col & 7);
}

// ------------- prep: weight bf16 convert + rpb expand + comboT table ----------
// comboT[w][h][j=key][i=query] = (rpb[h][i][j] + mask[w][i][j]) * LOG2E, -1e30 pad
__global__ void wmsa_prep(const float* __restrict__ qkv_w,
                          const float* __restrict__ out_w,
                          const float* __restrict__ rpb_table,
                          const float* __restrict__ mask,
                          bf16* __restrict__ qkv_wb,
                          bf16* __restrict__ out_wb,
                          float* __restrict__ rpbx,
                          float* __restrict__ comboT,
                          int build_combo) {
    int t = blockIdx.x * 256 + threadIdx.x;
    if (t < 110592) qkv_wb[t] = (bf16)qkv_w[t];
    if (t < 36864)  out_wb[t] = (bf16)out_w[t];
    if (t < 14406) {
        int h = t / 2401, ij = t % 2401, i = ij / 49, j = ij % 49;
        int ri = (i / 7 - j / 7 + 6) * 13 + (i % 7 - j % 7 + 6);
        rpbx[t] = rpb_table[ri * 6 + h];
    }
    if (build_combo && t < 64 * 6 * 64 * 64) {
        int i = t & 63, j = (t >> 6) & 63, r = t >> 12;  // i=query (inner), j=key
        int h = r % 6, w = r / 6;
        float v = -1e30f;
        if (i < 49 && j < 49) {
            int ri = (i / 7 - j / 7 + 6) * 13 + (i % 7 - j % 7 + 6);
            v = (rpb_table[ri * 6 + h] + mask[w * 2401 + i * 49 + j]) * LOG2E;
        }
        comboT[t] = v;
    }
}

// =================== fused kernel: one window per block, 12 waves =============
template <bool USE_COMBO>
__global__ __launch_bounds__(768, 3) void wmsa_fused(
    const float* __restrict__ x, const float* __restrict__ mask,
    const float* __restrict__ qkv_b, const float* __restrict__ out_b,
    const bf16* __restrict__ qkv_wb, const bf16* __restrict__ out_wb,
    const float* __restrict__ rpbx, const float* __restrict__ comboT,
    float* __restrict__ out)
{
    __shared__ __align__(16) bf16 s_x[12288];      // x window bf16 [64][192] swz
    __shared__ __align__(16) bf16 s_qp[6][2048];   // q, then P (per head)
    __shared__ __align__(16) bf16 s_kao[12288];    // k (per head), then ao[64][192]
    __shared__ __align__(16) bf16 s_vt[6][2048];   // v^T

    const int b    = blockIdx.x;
    const int tid  = threadIdx.x;
    const int wv   = tid >> 6;      // 0..11
    const int lane = tid & 63;
    const int lo   = lane & 15;
    const int hi   = lane >> 4;     // 0..3

    const float* xw    = x + (size_t)b * 9408;
    const int    obase = wv * 48;   // 48 qkv output cols per wave
    const int    sec   = wv >> 2;   // 0=q 1=k 2=v (uniform per wave)

    // ============ Phase 0: stage x (fp32 -> bf16) into LDS, zero-padded =======
    {
        const int c0 = tid;                       // rows 0..31
        const int r0s = c0 / 24, cc0 = c0 % 24;
        const float* p0 = xw + r0s * 192 + cc0 * 8;
        floatv4 f0 = *(const floatv4*)p0;
        floatv4 f1 = *(const floatv4*)(p0 + 4);
        bf16x8 v;
        v[0]=(bf16)f0[0]; v[1]=(bf16)f0[1]; v[2]=(bf16)f0[2]; v[3]=(bf16)f0[3];
        v[4]=(bf16)f1[0]; v[5]=(bf16)f1[1]; v[6]=(bf16)f1[2]; v[7]=(bf16)f1[3];
        *(bf16x8*)&s_x[(r0s * 24 + (cc0 ^ (r0s & 7))) * 8] = v;

        const int c1 = tid + 768;                 // rows 32..63 (zero >= 49)
        const int r1s = c1 / 24, cc1 = c1 % 24;
        bf16x8 w = {};
        if (r1s < 49) {
            const float* p1 = xw + r1s * 192 + cc1 * 8;
            floatv4 g0 = *(const floatv4*)p1;
            floatv4 g1 = *(const floatv4*)(p1 + 4);
            w[0]=(bf16)g0[0]; w[1]=(bf16)g0[1]; w[2]=(bf16)g0[2]; w[3]=(bf16)g0[3];
            w[4]=(bf16)g1[0]; w[5]=(bf16)g1[1]; w[6]=(bf16)g1[2]; w[7]=(bf16)g1[3];
        }
        *(bf16x8*)&s_x[(r1s * 24 + (cc1 ^ (r1s & 7))) * 8] = w;
    }
    __syncthreads();

    // ============ Phase 1: QKV = x @ qkv_w^T + qkv_b (A from LDS, B 2-deep) ===
#pragma unroll 1
    for (int mib = 0; mib < 2; ++mib) {
        f32x4 acc[2][3];
#pragma unroll
        for (int mi = 0; mi < 2; ++mi)
#pragma unroll
            for (int nj = 0; nj < 3; ++nj) acc[mi][nj] = (f32x4){0.f, 0.f, 0.f, 0.f};

        const int r0 = mib * 32 + lo;
        const int r1 = r0 + 16;        // rows >= 49 are zeros in s_x

        auto loadB = [&](bf16x8* dst, int kk) {
#pragma unroll
            for (int nj = 0; nj < 3; ++nj)
                dst[nj] = *(const bf16x8*)(qkv_wb + (obase + nj * 16 + lo) * 192 + kk * 32 + hi * 8);
        };

        bf16x8 b0_[3], b1_[3], b2_[3];
        loadB(b0_, 0);
        loadB(b1_, 1);
#pragma unroll
        for (int kk = 0; kk < 6; ++kk) {
            if (kk < 4) loadB(b2_, kk + 2);
            bf16x8 a0 = *(const bf16x8*)t192_ptr(s_x, r0, kk * 32 + hi * 8);
            bf16x8 a1 = *(const bf16x8*)t192_ptr(s_x, r1, kk * 32 + hi * 8);
            acc[0][0] = __builtin_amdgcn_mfma_f32_16x16x32_bf16(a0, b0_[0], acc[0][0], 0, 0, 0);
            acc[1][0] = __builtin_amdgcn_mfma_f32_16x16x32_bf16(a1, b0_[0], acc[1][0], 0, 0, 0);
            acc[0][1] = __builtin_amdgcn_mfma_f32_16x16x32_bf16(a0, b0_[1], acc[0][1], 0, 0, 0);
            acc[1][1] = __builtin_amdgcn_mfma_f32_16x16x32_bf16(a1, b0_[1], acc[1][1], 0, 0, 0);
            acc[0][2] = __builtin_amdgcn_mfma_f32_16x16x32_bf16(a0, b0_[2], acc[0][2], 0, 0, 0);
            acc[1][2] = __builtin_amdgcn_mfma_f32_16x16x32_bf16(a1, b0_[2], acc[1][2], 0, 0, 0);
            b0_[0] = b1_[0]; b0_[1] = b1_[1]; b0_[2] = b1_[2];
            b1_[0] = b2_[0]; b1_[1] = b2_[1]; b1_[2] = b2_[2];
        }

        // epilogue: bias + scatter into q / k / v^T LDS tiles
#pragma unroll
        for (int nj = 0; nj < 3; ++nj) {
            const int o    = obase + nj * 16 + lo;
            const float bs = qkv_b[o];
            const int oc   = o - sec * 192;
            const int hh   = oc >> 5;
            const int dd   = oc & 31;
#pragma unroll
            for (int mi = 0; mi < 2; ++mi)
#pragma unroll
                for (int r = 0; r < 4; ++r) {
                    const int n = mib * 32 + mi * 16 + hi * 4 + r;
                    const float v = acc[mi][nj][r] + bs;
                    if (sec == 0)      *qk_ptr(&s_qp[hh][0], n, dd)      = (bf16)(v * QK_SCALE2);
                    else if (sec == 1) *qk_ptr(s_kao + hh * 2048, n, dd) = (bf16)v;
                    else               *vt_ptr(&s_vt[hh][0], dd, n)      = (bf16)v;
                }
        }
    }
    __syncthreads();

    // ============ Phase 2: attention. wave = (head h, 32-row pass p) ==========
    {
        const int h    = wv >> 1;    // 0..5
        const int arow = (wv & 1) * 32;
        bf16* qb    = &s_qp[h][0];
        bf16* kbase = s_kao + h * 2048;

        // comboT loads: one floatv4 per (mi,nt) -- 8 dwordx4 instead of 32 dword
        f32x4 cv[2][4];
        if (USE_COMBO) {
            const float* cbT = comboT + (((size_t)(b & 63) * 6 + h) << 12);
#pragma unroll
            for (int mi = 0; mi < 2; ++mi)
#pragma unroll
                for (int nt = 0; nt < 4; ++nt)
                    cv[mi][nt] = *(const floatv4*)(cbT + (nt * 16 + lo) * 64
                                                   + arow + mi * 16 + hi * 4);
        }

        bf16x8 qa0 = *(const bf16x8*)qk_ptr(qb, arow + lo, hi * 8);
        bf16x8 qa1 = *(const bf16x8*)qk_ptr(qb, arow + 16 + lo, hi * 8);
        bf16x8 kb0 = *(const bf16x8*)qk_ptr(kbase,  0 + lo, hi * 8);
        bf16x8 kb1 = *(const bf16x8*)qk_ptr(kbase, 16 + lo, hi * 8);
        bf16x8 kb2 = *(const bf16x8*)qk_ptr(kbase, 32 + lo, hi * 8);
        bf16x8 kb3 = *(const bf16x8*)qk_ptr(kbase, 48 + lo, hi * 8);

        // all q/k fragment reads complete -> P-staging and ao overlay are safe
        __syncthreads();

        f32x4 s[2][4];
#pragma unroll
        for (int mi = 0; mi < 2; ++mi)
#pragma unroll
            for (int nt = 0; nt < 4; ++nt) s[mi][nt] = (f32x4){0.f, 0.f, 0.f, 0.f};
        s[0][0] = __builtin_amdgcn_mfma_f32_16x16x32_bf16(qa0, kb0, s[0][0], 0, 0, 0);
        s[0][1] = __builtin_amdgcn_mfma_f32_16x16x32_bf16(qa0, kb1, s[0][1], 0, 0, 0);
        s[0][2] = __builtin_amdgcn_mfma_f32_16x16x32_bf16(qa0, kb2, s[0][2], 0, 0, 0);
        s[0][3] = __builtin_amdgcn_mfma_f32_16x16x32_bf16(qa0, kb3, s[0][3], 0, 0, 0);
        s[1][0] = __builtin_amdgcn_mfma_f32_16x16x32_bf16(qa1, kb0, s[1][0], 0, 0, 0);
        s[1][1] = __builtin_amdgcn_mfma_f32_16x16x32_bf16(qa1, kb1, s[1][1], 0, 0, 0);
        s[1][2] = __builtin_amdgcn_mfma_f32_16x16x32_bf16(qa1, kb2, s[1][2], 0, 0, 0);
        s[1][3] = __builtin_amdgcn_mfma_f32_16x16x32_bf16(qa1, kb3, s[1][3], 0, 0, 0);

        if (USE_COMBO) {
            // cv[mi][nt][r] corresponds to query i = arow+mi*16+hi*4+r, key j = nt*16+lo
#pragma unroll
            for (int mi = 0; mi < 2; ++mi)
#pragma unroll
                for (int nt = 0; nt < 4; ++nt) s[mi][nt] += cv[mi][nt];
        } else {
            const float* mk = mask + (size_t)(b & 63) * 2401;
            const float* rb = rpbx + h * 2401;
#pragma unroll
            for (int nt = 0; nt < 4; ++nt) {
                const int j = nt * 16 + lo;
#pragma unroll
                for (int mi = 0; mi < 2; ++mi)
#pragma unroll
                    for (int r = 0; r < 4; ++r) {
                        const int i = arow + mi * 16 + hi * 4 + r;
                        float sv = s[mi][nt][r];
                        if (j >= 49 || i >= 49) sv = -1e30f;
                        else sv += (rb[i * 49 + j] + mk[i * 49 + j]) * LOG2E;
                        s[mi][nt][r] = sv;
                    }
            }
        }

        // softmax over j (exp2 domain; 4 regs x 16 lanes sharing hi)
#pragma unroll
        for (int mi = 0; mi < 2; ++mi)
#pragma unroll
            for (int r = 0; r < 4; ++r) {
                float m = fmaxf(fmaxf(s[mi][0][r], s[mi][1][r]),
                                fmaxf(s[mi][2][r], s[mi][3][r]));
                m = fmaxf(m, __shfl_xor(m, 1));
                m = fmaxf(m, __shfl_xor(m, 2));
                m = fmaxf(m, __shfl_xor(m, 4));
                m = fmaxf(m, __shfl_xor(m, 8));
                float sum = 0.f;
#pragma unroll
                for (int nt = 0; nt < 4; ++nt) {
                    float pv = exp2f(s[mi][nt][r] - m);
                    s[mi][nt][r] = pv;
                    sum += pv;
                }
                sum += __shfl_xor(sum, 1);
                sum += __shfl_xor(sum, 2);
                sum += __shfl_xor(sum, 4);
                sum += __shfl_xor(sum, 8);
                const float inv = 1.0f / sum;
#pragma unroll
                for (int nt = 0; nt < 4; ++nt) s[mi][nt][r] *= inv;
            }

        // PV: rows arow..arow+31; P staged into this pass's own q rows
        f32x4 o00 = (f32x4){0.f,0.f,0.f,0.f}, o01 = (f32x4){0.f,0.f,0.f,0.f};
        f32x4 o10 = (f32x4){0.f,0.f,0.f,0.f}, o11 = (f32x4){0.f,0.f,0.f,0.f};
#pragma unroll
        for (int kk = 0; kk < 2; ++kk) {
#pragma unroll
            for (int mi = 0; mi < 2; ++mi)
#pragma unroll
                for (int c = 0; c < 2; ++c) {
                    const int nt = kk * 2 + c;
#pragma unroll
                    for (int r = 0; r < 4; ++r)
                        *qk_ptr(qb, arow + mi * 16 + hi * 4 + r, c * 16 + lo) =
                            (bf16)s[mi][nt][r];
                }
            bf16x8 pa0 = *(const bf16x8*)qk_ptr(qb, arow + lo, hi * 8);
            bf16x8 pa1 = *(const bf16x8*)qk_ptr(qb, arow + 16 + lo, hi * 8);
            bf16x8 vb0 = *(const bf16x8*)vt_ptr(&s_vt[h][0],  0 + lo, kk * 32 + hi * 8);
            bf16x8 vb1 = *(const bf16x8*)vt_ptr(&s_vt[h][0], 16 + lo, kk * 32 + hi * 8);
            o00 = __builtin_amdgcn_mfma_f32_16x16x32_bf16(pa0, vb0, o00, 0, 0, 0);
            o10 = __builtin_amdgcn_mfma_f32_16x16x32_bf16(pa1, vb0, o10, 0, 0, 0);
            o01 = __builtin_amdgcn_mfma_f32_16x16x32_bf16(pa0, vb1, o01, 0, 0, 0);
            o11 = __builtin_amdgcn_mfma_f32_16x16x32_bf16(pa1, vb1, o11, 0, 0, 0);
        }

        // scatter head output into ao (overlays k; safe post-barrier)
#pragma unroll
        for (int r = 0; r < 4; ++r) {
            const int n0 = arow + hi * 4 + r;
            const int n1 = n0 + 16;
            *t192_ptr(s_kao, n0, h * 32 +  0 + lo) = (bf16)o00[r];
            *t192_ptr(s_kao, n0, h * 32 + 16 + lo) = (bf16)o01[r];
            *t192_ptr(s_kao, n1, h * 32 +  0 + lo) = (bf16)o10[r];
            *t192_ptr(s_kao, n1, h * 32 + 16 + lo) = (bf16)o11[r];
        }
    }
    __syncthreads();

    // ============ Phase 3: out = ao @ out_w^T + out_b (1 col-tile per wave) ===
    {
        const int o2 = wv * 16 + lo;           // 0..191
        f32x4 facc[4];
#pragma unroll
        for (int mi = 0; mi < 4; ++mi) facc[mi] = (f32x4){0.f, 0.f, 0.f, 0.f};

        bf16x8 fbc = *(const bf16x8*)(out_wb + o2 * 192 + hi * 8);
#pragma unroll
        for (int kk = 0; kk < 6; ++kk) {
            bf16x8 fbn;
            if (kk < 5) fbn = *(const bf16x8*)(out_wb + o2 * 192 + (kk + 1) * 32 + hi * 8);
            bf16x8 fa[4];
#pragma unroll
            for (int mi = 0; mi < 4; ++mi)
                fa[mi] = *(const bf16x8*)t192_ptr(s_kao, mi * 16 + lo, kk * 32 + hi * 8);
#pragma unroll
            for (int mi = 0; mi < 4; ++mi)
                facc[mi] = __builtin_amdgcn_mfma_f32_16x16x32_bf16(fa[mi], fbc, facc[mi], 0, 0, 0);
            fbc = fbn;
        }

        const float ob = out_b[o2];
        float* ow = out + (size_t)b * 9408;
#pragma unroll
        for (int mi = 0; mi < 4; ++mi)
#pragma unroll
            for (int r = 0; r < 4; ++r) {
                const int n = mi * 16 + hi * 4 + r;
                if (n < 49) ow[n * 192 + o2] = facc[mi][r] + ob;
            }
    }
}

extern "C" void kernel_launch(void* const* d_in, const int* in_sizes, int n_in,
                              void* d_out, int out_size, void* d_ws, size_t ws_size,
                              hipStream_t stream) {
    const float* x      = (const float*)d_in[0];
    const float* mask   = (const float*)d_in[1];
    const float* qkv_w  = (const float*)d_in[2];
    const float* qkv_b  = (const float*)d_in[3];
    const float* out_w  = (const float*)d_in[4];
    const float* out_b  = (const float*)d_in[5];
    const float* rpb    = (const float*)d_in[6];
    float* out          = (float*)d_out;

    char* ws = (char*)d_ws;
    bf16*  qkv_wb = (bf16*)ws;                       // 110592 * 2 = 221184 B
    bf16*  out_wb = (bf16*)(ws + 221184);            //  36864 * 2 =  73728 B
    float* rpbx   = (float*)(ws + 294912);           //  14406 * 4 =  57624 B
    float* comboT = (float*)(ws + 352768);           // 1572864 * 4 = 6291456 B
    const bool use_combo = ws_size >= (size_t)(352768 + 6291456);

    hipLaunchKernelGGL(wmsa_prep, dim3(6144), dim3(256), 0, stream,
                       qkv_w, out_w, rpb, mask, qkv_wb, out_wb, rpbx, comboT,
                       use_combo ? 1 : 0);
    if (use_combo)
        hipLaunchKernelGGL(HIP_KERNEL_NAME(wmsa_fused<true>), dim3(4096), dim3(768), 0, stream,
                           x, mask, qkv_b, out_b, qkv_wb, out_wb, rpbx, comboT, out);
    else
        hipLaunchKernelGGL(HIP_KERNEL_NAME(wmsa_fused<false>), dim3(4096), dim3(768), 0, stream,
                           x, mask, qkv_b, out_b, qkv_wb, out_wb, rpbx, comboT, out);
}

// Round 13
// 274.757 us; speedup vs baseline: 3.0697x; 1.2430x over previous
//
#include <hip/hip_runtime.h>
#include <hip/hip_bf16.h>

typedef __bf16 bf16;
typedef __bf16 bf16x4 __attribute__((ext_vector_type(4)));
typedef __bf16 bf16x8 __attribute__((ext_vector_type(8)));
typedef float f32x4 __attribute__((ext_vector_type(4)));
typedef float floatv4 __attribute__((ext_vector_type(4)));

#define QK_SCALE 0.17677669529663687f

// ---- swizzled LDS addressing -------------------------------------------------
// q/k tiles: [64][32] bf16 per head (row = 64B = 4 x 16B chunks).
__device__ __forceinline__ bf16* qk_ptr(bf16* base, int row, int col) {
    return base + row * 32 + ((((col >> 3) ^ ((row >> 1) & 3)) << 3)) + (col & 7);
}
// vt tile: [32][64] bf16 per head (row = 128B = 8 chunks). chunk' = chunk ^ (row&7).
__device__ __forceinline__ bf16* vt_ptr(bf16* base, int row, int col) {
    return base + row * 64 + ((((col >> 3) ^ (row & 7)) << 3)) + (col & 7);
}
// 192-col tiles (x staging / ao): 24 16B-chunks/row, chunk' = chunk ^ (row&7).
__device__ __forceinline__ bf16* t192_ptr(bf16* base, int row, int col) {
    return base + row * 192 + ((((col >> 3) ^ (row & 7)) << 3)) + (col & 7);
}

// ---------------- prep: weight bf16 convert + rpb expand + combo table --------
__global__ void wmsa_prep(const float* __restrict__ qkv_w,
                          const float* __restrict__ out_w,
                          const float* __restrict__ rpb_table,
                          const float* __restrict__ mask,
                          bf16* __restrict__ qkv_wb,
                          bf16* __restrict__ out_wb,
                          float* __restrict__ rpbx,
                          float* __restrict__ combo,
                          int build_combo) {
    int t = blockIdx.x * 256 + threadIdx.x;
    if (t < 110592) qkv_wb[t] = (bf16)qkv_w[t];
    if (t < 36864)  out_wb[t] = (bf16)out_w[t];
    if (t < 14406) {
        int h = t / 2401, ij = t % 2401, i = ij / 49, j = ij % 49;
        int ri = (i / 7 - j / 7 + 6) * 13 + (i % 7 - j % 7 + 6);
        rpbx[t] = rpb_table[ri * 6 + h];
    }
    if (build_combo && t < 64 * 6 * 64 * 64) {
        int j = t & 63, i = (t >> 6) & 63, r = t >> 12;
        int h = r % 6, w = r / 6;
        float v = -1e30f;
        if (i < 49 && j < 49) {
            int ri = (i / 7 - j / 7 + 6) * 13 + (i % 7 - j % 7 + 6);
            v = rpb_table[ri * 6 + h] + mask[w * 2401 + i * 49 + j];
        }
        combo[t] = v;
    }
}

// =================== fused kernel: one window per block, 12 waves =============
// 3 barriers total; phase 2 is fully decoupled per wave (ao -> dead s_x).
template <bool USE_COMBO>
__global__ __launch_bounds__(768, 3) void wmsa_fused(
    const float* __restrict__ x, const float* __restrict__ mask,
    const float* __restrict__ qkv_b, const float* __restrict__ out_b,
    const bf16* __restrict__ qkv_wb, const bf16* __restrict__ out_wb,
    const float* __restrict__ rpbx, const float* __restrict__ combo,
    float* __restrict__ out)
{
    __shared__ __align__(16) bf16 s_x[12288];      // x [64][192] swz; later ao
    __shared__ __align__(16) bf16 s_qp[6][2048];   // q, then P (per head)
    __shared__ __align__(16) bf16 s_k[6][2048];    // k (per head)
    __shared__ __align__(16) bf16 s_vt[6][2048];   // v^T

    const int b    = blockIdx.x;
    const int tid  = threadIdx.x;
    const int wv   = tid >> 6;      // 0..11
    const int lane = tid & 63;
    const int lo   = lane & 15;
    const int hi   = lane >> 4;     // 0..3

    const float* xw    = x + (size_t)b * 9408;
    const int    obase = wv * 48;   // 48 qkv output cols per wave
    const int    sec   = wv >> 2;   // 0=q 1=k 2=v (uniform per wave)

    // ============ Phase 0: stage x (fp32 -> bf16) into LDS, zero-padded =======
    {
        const int c0 = tid;                       // rows 0..31
        const int r0s = c0 / 24, cc0 = c0 % 24;
        const float* p0 = xw + r0s * 192 + cc0 * 8;
        floatv4 f0 = *(const floatv4*)p0;
        floatv4 f1 = *(const floatv4*)(p0 + 4);
        bf16x8 v;
        v[0]=(bf16)f0[0]; v[1]=(bf16)f0[1]; v[2]=(bf16)f0[2]; v[3]=(bf16)f0[3];
        v[4]=(bf16)f1[0]; v[5]=(bf16)f1[1]; v[6]=(bf16)f1[2]; v[7]=(bf16)f1[3];
        *(bf16x8*)&s_x[(r0s * 24 + (cc0 ^ (r0s & 7))) * 8] = v;

        const int c1 = tid + 768;                 // rows 32..63 (zero >= 49)
        const int r1s = c1 / 24, cc1 = c1 % 24;
        bf16x8 w = {};
        if (r1s < 49) {
            const float* p1 = xw + r1s * 192 + cc1 * 8;
            floatv4 g0 = *(const floatv4*)p1;
            floatv4 g1 = *(const floatv4*)(p1 + 4);
            w[0]=(bf16)g0[0]; w[1]=(bf16)g0[1]; w[2]=(bf16)g0[2]; w[3]=(bf16)g0[3];
            w[4]=(bf16)g1[0]; w[5]=(bf16)g1[1]; w[6]=(bf16)g1[2]; w[7]=(bf16)g1[3];
        }
        *(bf16x8*)&s_x[(r1s * 24 + (cc1 ^ (r1s & 7))) * 8] = w;
    }
    __syncthreads();                               // barrier 1: x visible

    // ============ Phase 1: QKV = x @ qkv_w^T + qkv_b (A from LDS, B 2-deep) ===
#pragma unroll 1
    for (int mib = 0; mib < 2; ++mib) {
        f32x4 acc[2][3];
#pragma unroll
        for (int mi = 0; mi < 2; ++mi)
#pragma unroll
            for (int nj = 0; nj < 3; ++nj) acc[mi][nj] = (f32x4){0.f, 0.f, 0.f, 0.f};

        const int r0 = mib * 32 + lo;
        const int r1 = r0 + 16;        // rows >= 49 are zeros in s_x

        auto loadB = [&](bf16x8* dst, int kk) {
#pragma unroll
            for (int nj = 0; nj < 3; ++nj)
                dst[nj] = *(const bf16x8*)(qkv_wb + (obase + nj * 16 + lo) * 192 + kk * 32 + hi * 8);
        };

        bf16x8 b0_[3], b1_[3], b2_[3];
        loadB(b0_, 0);
        loadB(b1_, 1);
#pragma unroll
        for (int kk = 0; kk < 6; ++kk) {
            if (kk < 4) loadB(b2_, kk + 2);
            bf16x8 a0 = *(const bf16x8*)t192_ptr(s_x, r0, kk * 32 + hi * 8);
            bf16x8 a1 = *(const bf16x8*)t192_ptr(s_x, r1, kk * 32 + hi * 8);
            acc[0][0] = __builtin_amdgcn_mfma_f32_16x16x32_bf16(a0, b0_[0], acc[0][0], 0, 0, 0);
            acc[1][0] = __builtin_amdgcn_mfma_f32_16x16x32_bf16(a1, b0_[0], acc[1][0], 0, 0, 0);
            acc[0][1] = __builtin_amdgcn_mfma_f32_16x16x32_bf16(a0, b0_[1], acc[0][1], 0, 0, 0);
            acc[1][1] = __builtin_amdgcn_mfma_f32_16x16x32_bf16(a1, b0_[1], acc[1][1], 0, 0, 0);
            acc[0][2] = __builtin_amdgcn_mfma_f32_16x16x32_bf16(a0, b0_[2], acc[0][2], 0, 0, 0);
            acc[1][2] = __builtin_amdgcn_mfma_f32_16x16x32_bf16(a1, b0_[2], acc[1][2], 0, 0, 0);
            b0_[0] = b1_[0]; b0_[1] = b1_[1]; b0_[2] = b1_[2];
            b1_[0] = b2_[0]; b1_[1] = b2_[1]; b1_[2] = b2_[2];
        }

        // epilogue: bias + scatter into q / k / v^T LDS tiles
        if (sec < 2) {
#pragma unroll
            for (int nj = 0; nj < 3; ++nj) {
                const int o    = obase + nj * 16 + lo;
                const float bs = qkv_b[o];
                const int oc   = o - sec * 192;
                const int hh   = oc >> 5;
                const int dd   = oc & 31;
                bf16* base = (sec == 0) ? &s_qp[hh][0] : &s_k[hh][0];
#pragma unroll
                for (int mi = 0; mi < 2; ++mi)
#pragma unroll
                    for (int r = 0; r < 4; ++r) {
                        const int n = mib * 32 + mi * 16 + hi * 4 + r;
                        const float v = acc[mi][nj][r] + bs;
                        *qk_ptr(base, n, dd) = (sec == 0) ? (bf16)(v * QK_SCALE) : (bf16)v;
                    }
            }
        } else {
            // v waves: rows n contiguous in r -> vectorized b64 stores into vt
#pragma unroll
            for (int nj = 0; nj < 3; ++nj) {
                const int o    = obase + nj * 16 + lo;
                const float bs = qkv_b[o];
                const int oc   = o - 384;
                const int hh   = oc >> 5;
                const int dd   = oc & 31;
#pragma unroll
                for (int mi = 0; mi < 2; ++mi) {
                    const int n0 = mib * 32 + mi * 16 + hi * 4;
                    bf16x4 pk;
#pragma unroll
                    for (int r = 0; r < 4; ++r) pk[r] = (bf16)(acc[mi][nj][r] + bs);
                    *(bf16x4*)vt_ptr(&s_vt[hh][0], dd, n0) = pk;
                }
            }
        }
    }
    __syncthreads();                               // barrier 2: q/k/vt visible

    // ====== Phase 2: attention, fully per-wave decoupled (no barriers) ========
    {
        const int h    = wv >> 1;    // 0..5
        const int arow = (wv & 1) * 32;
        bf16* qb    = &s_qp[h][0];
        bf16* kbase = &s_k[h][0];

        // combo loads issued first (latency hidden under LDS reads + MFMA)
        f32x4 cv[2][4];
        if (USE_COMBO) {
            const float* cb = combo + (((size_t)(b & 63) * 6 + h) << 12);
#pragma unroll
            for (int mi = 0; mi < 2; ++mi)
#pragma unroll
                for (int nt = 0; nt < 4; ++nt)
#pragma unroll
                    for (int r = 0; r < 4; ++r)
                        cv[mi][nt][r] = cb[(arow + mi * 16 + hi * 4 + r) * 64 + nt * 16 + lo];
        }

        bf16x8 qa0 = *(const bf16x8*)qk_ptr(qb, arow + lo, hi * 8);
        bf16x8 qa1 = *(const bf16x8*)qk_ptr(qb, arow + 16 + lo, hi * 8);
        bf16x8 kb0 = *(const bf16x8*)qk_ptr(kbase,  0 + lo, hi * 8);
        bf16x8 kb1 = *(const bf16x8*)qk_ptr(kbase, 16 + lo, hi * 8);
        bf16x8 kb2 = *(const bf16x8*)qk_ptr(kbase, 32 + lo, hi * 8);
        bf16x8 kb3 = *(const bf16x8*)qk_ptr(kbase, 48 + lo, hi * 8);

        f32x4 s[2][4];
#pragma unroll
        for (int mi = 0; mi < 2; ++mi)
#pragma unroll
            for (int nt = 0; nt < 4; ++nt) s[mi][nt] = (f32x4){0.f, 0.f, 0.f, 0.f};
        s[0][0] = __builtin_amdgcn_mfma_f32_16x16x32_bf16(qa0, kb0, s[0][0], 0, 0, 0);
        s[0][1] = __builtin_amdgcn_mfma_f32_16x16x32_bf16(qa0, kb1, s[0][1], 0, 0, 0);
        s[0][2] = __builtin_amdgcn_mfma_f32_16x16x32_bf16(qa0, kb2, s[0][2], 0, 0, 0);
        s[0][3] = __builtin_amdgcn_mfma_f32_16x16x32_bf16(qa0, kb3, s[0][3], 0, 0, 0);
        s[1][0] = __builtin_amdgcn_mfma_f32_16x16x32_bf16(qa1, kb0, s[1][0], 0, 0, 0);
        s[1][1] = __builtin_amdgcn_mfma_f32_16x16x32_bf16(qa1, kb1, s[1][1], 0, 0, 0);
        s[1][2] = __builtin_amdgcn_mfma_f32_16x16x32_bf16(qa1, kb2, s[1][2], 0, 0, 0);
        s[1][3] = __builtin_amdgcn_mfma_f32_16x16x32_bf16(qa1, kb3, s[1][3], 0, 0, 0);

        if (USE_COMBO) {
#pragma unroll
            for (int mi = 0; mi < 2; ++mi)
#pragma unroll
                for (int nt = 0; nt < 4; ++nt) s[mi][nt] += cv[mi][nt];
        } else {
            const float* mk = mask + (size_t)(b & 63) * 2401;
            const float* rb = rpbx + h * 2401;
#pragma unroll
            for (int nt = 0; nt < 4; ++nt) {
                const int j = nt * 16 + lo;
#pragma unroll
                for (int mi = 0; mi < 2; ++mi)
#pragma unroll
                    for (int r = 0; r < 4; ++r) {
                        const int i = arow + mi * 16 + hi * 4 + r;
                        float sv = s[mi][nt][r];
                        if (j >= 49 || i >= 49) sv = -1e30f;
                        else sv += rb[i * 49 + j] + mk[i * 49 + j];
                        s[mi][nt][r] = sv;
                    }
            }
        }

        // softmax over j (4 regs x 16 lanes sharing hi)
#pragma unroll
        for (int mi = 0; mi < 2; ++mi)
#pragma unroll
            for (int r = 0; r < 4; ++r) {
                float m = fmaxf(fmaxf(s[mi][0][r], s[mi][1][r]),
                                fmaxf(s[mi][2][r], s[mi][3][r]));
                m = fmaxf(m, __shfl_xor(m, 1));
                m = fmaxf(m, __shfl_xor(m, 2));
                m = fmaxf(m, __shfl_xor(m, 4));
                m = fmaxf(m, __shfl_xor(m, 8));
                float sum = 0.f;
#pragma unroll
                for (int nt = 0; nt < 4; ++nt) {
                    float pv = __expf(s[mi][nt][r] - m);
                    s[mi][nt][r] = pv;
                    sum += pv;
                }
                sum += __shfl_xor(sum, 1);
                sum += __shfl_xor(sum, 2);
                sum += __shfl_xor(sum, 4);
                sum += __shfl_xor(sum, 8);
                const float inv = 1.0f / sum;
#pragma unroll
                for (int nt = 0; nt < 4; ++nt) s[mi][nt][r] *= inv;
            }

        // PV: rows arow..arow+31; P staged into this pass's OWN q rows
        // (sibling wave of head h only ever reads the other 32 rows -> no race)
        f32x4 o00 = (f32x4){0.f,0.f,0.f,0.f}, o01 = (f32x4){0.f,0.f,0.f,0.f};
        f32x4 o10 = (f32x4){0.f,0.f,0.f,0.f}, o11 = (f32x4){0.f,0.f,0.f,0.f};
#pragma unroll
        for (int kk = 0; kk < 2; ++kk) {
#pragma unroll
            for (int mi = 0; mi < 2; ++mi)
#pragma unroll
                for (int c = 0; c < 2; ++c) {
                    const int nt = kk * 2 + c;
#pragma unroll
                    for (int r = 0; r < 4; ++r)
                        *qk_ptr(qb, arow + mi * 16 + hi * 4 + r, c * 16 + lo) =
                            (bf16)s[mi][nt][r];
                }
            bf16x8 pa0 = *(const bf16x8*)qk_ptr(qb, arow + lo, hi * 8);
            bf16x8 pa1 = *(const bf16x8*)qk_ptr(qb, arow + 16 + lo, hi * 8);
            bf16x8 vb0 = *(const bf16x8*)vt_ptr(&s_vt[h][0],  0 + lo, kk * 32 + hi * 8);
            bf16x8 vb1 = *(const bf16x8*)vt_ptr(&s_vt[h][0], 16 + lo, kk * 32 + hi * 8);
            o00 = __builtin_amdgcn_mfma_f32_16x16x32_bf16(pa0, vb0, o00, 0, 0, 0);
            o10 = __builtin_amdgcn_mfma_f32_16x16x32_bf16(pa1, vb0, o10, 0, 0, 0);
            o01 = __builtin_amdgcn_mfma_f32_16x16x32_bf16(pa0, vb1, o01, 0, 0, 0);
            o11 = __builtin_amdgcn_mfma_f32_16x16x32_bf16(pa1, vb1, o11, 0, 0, 0);
        }

        // scatter head output into ao = s_x (dead after phase 1; no race)
#pragma unroll
        for (int r = 0; r < 4; ++r) {
            const int n0 = arow + hi * 4 + r;
            const int n1 = n0 + 16;
            *t192_ptr(s_x, n0, h * 32 +  0 + lo) = (bf16)o00[r];
            *t192_ptr(s_x, n0, h * 32 + 16 + lo) = (bf16)o01[r];
            *t192_ptr(s_x, n1, h * 32 +  0 + lo) = (bf16)o10[r];
            *t192_ptr(s_x, n1, h * 32 + 16 + lo) = (bf16)o11[r];
        }
    }
    __syncthreads();                               // barrier 3: ao visible

    // ============ Phase 3: out = ao @ out_w^T + out_b (1 col-tile per wave) ===
    {
        const int o2 = wv * 16 + lo;           // 0..191
        f32x4 facc[4];
#pragma unroll
        for (int mi = 0; mi < 4; ++mi) facc[mi] = (f32x4){0.f, 0.f, 0.f, 0.f};

        bf16x8 fbc = *(const bf16x8*)(out_wb + o2 * 192 + hi * 8);
#pragma unroll
        for (int kk = 0; kk < 6; ++kk) {
            bf16x8 fbn;
            if (kk < 5) fbn = *(const bf16x8*)(out_wb + o2 * 192 + (kk + 1) * 32 + hi * 8);
            bf16x8 fa[4];
#pragma unroll
            for (int mi = 0; mi < 4; ++mi)
                fa[mi] = *(const bf16x8*)t192_ptr(s_x, mi * 16 + lo, kk * 32 + hi * 8);
#pragma unroll
            for (int mi = 0; mi < 4; ++mi)
                facc[mi] = __builtin_amdgcn_mfma_f32_16x16x32_bf16(fa[mi], fbc, facc[mi], 0, 0, 0);
            fbc = fbn;
        }

        const float ob = out_b[o2];
        float* ow = out + (size_t)b * 9408;
#pragma unroll
        for (int mi = 0; mi < 4; ++mi)
#pragma unroll
            for (int r = 0; r < 4; ++r) {
                const int n = mi * 16 + hi * 4 + r;
                if (n < 49) ow[n * 192 + o2] = facc[mi][r] + ob;
            }
    }
}

extern "C" void kernel_launch(void* const* d_in, const int* in_sizes, int n_in,
                              void* d_out, int out_size, void* d_ws, size_t ws_size,
                              hipStream_t stream) {
    const float* x      = (const float*)d_in[0];
    const float* mask   = (const float*)d_in[1];
    const float* qkv_w  = (const float*)d_in[2];
    const float* qkv_b  = (const float*)d_in[3];
    const float* out_w  = (const float*)d_in[4];
    const float* out_b  = (const float*)d_in[5];
    const float* rpb    = (const float*)d_in[6];
    float* out          = (float*)d_out;

    char* ws = (char*)d_ws;
    bf16*  qkv_wb = (bf16*)ws;                       // 110592 * 2 = 221184 B
    bf16*  out_wb = (bf16*)(ws + 221184);            //  36864 * 2 =  73728 B
    float* rpbx   = (float*)(ws + 294912);           //  14406 * 4 =  57624 B
    float* combo  = (float*)(ws + 352768);           // 1572864 * 4 = 6291456 B
    const bool use_combo = ws_size >= (size_t)(352768 + 6291456);

    hipLaunchKernelGGL(wmsa_prep, dim3(6144), dim3(256), 0, stream,
                       qkv_w, out_w, rpb, mask, qkv_wb, out_wb, rpbx, combo,
                       use_combo ? 1 : 0);
    if (use_combo)
        hipLaunchKernelGGL(HIP_KERNEL_NAME(wmsa_fused<true>), dim3(4096), dim3(768), 0, stream,
                           x, mask, qkv_b, out_b, qkv_wb, out_wb, rpbx, combo, out);
    else
        hipLaunchKernelGGL(HIP_KERNEL_NAME(wmsa_fused<false>), dim3(4096), dim3(768), 0, stream,
                           x, mask, qkv_b, out_b, qkv_wb, out_wb, rpbx, combo, out);
}

// Round 14
// 273.260 us; speedup vs baseline: 3.0865x; 1.0055x over previous
//
#include <hip/hip_runtime.h>
#include <hip/hip_bf16.h>

typedef __bf16 bf16;
typedef __bf16 bf16x4 __attribute__((ext_vector_type(4)));
typedef __bf16 bf16x8 __attribute__((ext_vector_type(8)));
typedef float f32x4 __attribute__((ext_vector_type(4)));
typedef float floatv4 __attribute__((ext_vector_type(4)));

#define QK_SCALE 0.17677669529663687f

// ---- padded affine LDS addressing (no XOR swizzle) ---------------------------
// x/ao tile [64][200]: row stride 400B = 100 banks = +4 mod 32 -> 2-way max.
#define X_LD 200
// q/k tiles [64][40]: row stride 80B = 20 banks -> starts {0,20,8,28,...} 2-way.
#define QK_LD 40
// vt tiles [32][72]: row stride 144B = 36 banks = +4 mod 32 -> 2-way max.
#define VT_LD 72

__device__ __forceinline__ bf16* x_ptr(bf16* base, int row, int col) {
    return base + row * X_LD + col;
}
__device__ __forceinline__ bf16* qk_ptr(bf16* base, int row, int col) {
    return base + row * QK_LD + col;
}
__device__ __forceinline__ bf16* vt_ptr(bf16* base, int row, int col) {
    return base + row * VT_LD + col;
}

// ---------------- prep: weight bf16 convert + rpb expand + combo table --------
__global__ void wmsa_prep(const float* __restrict__ qkv_w,
                          const float* __restrict__ out_w,
                          const float* __restrict__ rpb_table,
                          const float* __restrict__ mask,
                          bf16* __restrict__ qkv_wb,
                          bf16* __restrict__ out_wb,
                          float* __restrict__ rpbx,
                          float* __restrict__ combo,
                          int build_combo) {
    int t = blockIdx.x * 256 + threadIdx.x;
    if (t < 110592) qkv_wb[t] = (bf16)qkv_w[t];
    if (t < 36864)  out_wb[t] = (bf16)out_w[t];
    if (t < 14406) {
        int h = t / 2401, ij = t % 2401, i = ij / 49, j = ij % 49;
        int ri = (i / 7 - j / 7 + 6) * 13 + (i % 7 - j % 7 + 6);
        rpbx[t] = rpb_table[ri * 6 + h];
    }
    if (build_combo && t < 64 * 6 * 64 * 64) {
        int j = t & 63, i = (t >> 6) & 63, r = t >> 12;
        int h = r % 6, w = r / 6;
        float v = -1e30f;
        if (i < 49 && j < 49) {
            int ri = (i / 7 - j / 7 + 6) * 13 + (i % 7 - j % 7 + 6);
            v = rpb_table[ri * 6 + h] + mask[w * 2401 + i * 49 + j];
        }
        combo[t] = v;
    }
}

// =================== fused kernel: one window per block, 12 waves =============
// r13 structure (3 barriers, phase-2 decoupled, ao -> dead s_x), padded affine LDS.
template <bool USE_COMBO>
__global__ __launch_bounds__(768, 3) void wmsa_fused(
    const float* __restrict__ x, const float* __restrict__ mask,
    const float* __restrict__ qkv_b, const float* __restrict__ out_b,
    const bf16* __restrict__ qkv_wb, const bf16* __restrict__ out_wb,
    const float* __restrict__ rpbx, const float* __restrict__ combo,
    float* __restrict__ out)
{
    __shared__ __align__(16) bf16 s_x[64 * X_LD];     // x [64][200]; later ao
    __shared__ __align__(16) bf16 s_qp[6][64 * QK_LD];// q, then P (per head)
    __shared__ __align__(16) bf16 s_k[6][64 * QK_LD]; // k (per head)
    __shared__ __align__(16) bf16 s_vt[6][32 * VT_LD];// v^T

    const int b    = blockIdx.x;
    const int tid  = threadIdx.x;
    const int wv   = tid >> 6;      // 0..11
    const int lane = tid & 63;
    const int lo   = lane & 15;
    const int hi   = lane >> 4;     // 0..3

    const float* xw    = x + (size_t)b * 9408;
    const int    obase = wv * 48;   // 48 qkv output cols per wave
    const int    sec   = wv >> 2;   // 0=q 1=k 2=v (uniform per wave)

    // ============ Phase 0: stage x (fp32 -> bf16) into LDS, zero-padded =======
    {
        const int c0 = tid;                       // rows 0..31
        const int r0s = c0 / 24, cc0 = c0 % 24;
        const float* p0 = xw + r0s * 192 + cc0 * 8;
        floatv4 f0 = *(const floatv4*)p0;
        floatv4 f1 = *(const floatv4*)(p0 + 4);
        bf16x8 v;
        v[0]=(bf16)f0[0]; v[1]=(bf16)f0[1]; v[2]=(bf16)f0[2]; v[3]=(bf16)f0[3];
        v[4]=(bf16)f1[0]; v[5]=(bf16)f1[1]; v[6]=(bf16)f1[2]; v[7]=(bf16)f1[3];
        *(bf16x8*)&s_x[r0s * X_LD + cc0 * 8] = v;

        const int c1 = tid + 768;                 // rows 32..63 (zero >= 49)
        const int r1s = c1 / 24, cc1 = c1 % 24;
        bf16x8 w = {};
        if (r1s < 49) {
            const float* p1 = xw + r1s * 192 + cc1 * 8;
            floatv4 g0 = *(const floatv4*)p1;
            floatv4 g1 = *(const floatv4*)(p1 + 4);
            w[0]=(bf16)g0[0]; w[1]=(bf16)g0[1]; w[2]=(bf16)g0[2]; w[3]=(bf16)g0[3];
            w[4]=(bf16)g1[0]; w[5]=(bf16)g1[1]; w[6]=(bf16)g1[2]; w[7]=(bf16)g1[3];
        }
        *(bf16x8*)&s_x[r1s * X_LD + cc1 * 8] = w;
    }
    __syncthreads();                               // barrier 1: x visible

    // ============ Phase 1: QKV = x @ qkv_w^T + qkv_b (A from LDS, B 2-deep) ===
#pragma unroll 1
    for (int mib = 0; mib < 2; ++mib) {
        f32x4 acc[2][3];
#pragma unroll
        for (int mi = 0; mi < 2; ++mi)
#pragma unroll
            for (int nj = 0; nj < 3; ++nj) acc[mi][nj] = (f32x4){0.f, 0.f, 0.f, 0.f};

        const int r0 = mib * 32 + lo;
        const int r1 = r0 + 16;        // rows >= 49 are zeros in s_x

        auto loadB = [&](bf16x8* dst, int kk) {
#pragma unroll
            for (int nj = 0; nj < 3; ++nj)
                dst[nj] = *(const bf16x8*)(qkv_wb + (obase + nj * 16 + lo) * 192 + kk * 32 + hi * 8);
        };

        bf16x8 b0_[3], b1_[3], b2_[3];
        loadB(b0_, 0);
        loadB(b1_, 1);
#pragma unroll
        for (int kk = 0; kk < 6; ++kk) {
            if (kk < 4) loadB(b2_, kk + 2);
            bf16x8 a0 = *(const bf16x8*)x_ptr(s_x, r0, kk * 32 + hi * 8);
            bf16x8 a1 = *(const bf16x8*)x_ptr(s_x, r1, kk * 32 + hi * 8);
            acc[0][0] = __builtin_amdgcn_mfma_f32_16x16x32_bf16(a0, b0_[0], acc[0][0], 0, 0, 0);
            acc[1][0] = __builtin_amdgcn_mfma_f32_16x16x32_bf16(a1, b0_[0], acc[1][0], 0, 0, 0);
            acc[0][1] = __builtin_amdgcn_mfma_f32_16x16x32_bf16(a0, b0_[1], acc[0][1], 0, 0, 0);
            acc[1][1] = __builtin_amdgcn_mfma_f32_16x16x32_bf16(a1, b0_[1], acc[1][1], 0, 0, 0);
            acc[0][2] = __builtin_amdgcn_mfma_f32_16x16x32_bf16(a0, b0_[2], acc[0][2], 0, 0, 0);
            acc[1][2] = __builtin_amdgcn_mfma_f32_16x16x32_bf16(a1, b0_[2], acc[1][2], 0, 0, 0);
            b0_[0] = b1_[0]; b0_[1] = b1_[1]; b0_[2] = b1_[2];
            b1_[0] = b2_[0]; b1_[1] = b2_[1]; b1_[2] = b2_[2];
        }

        // epilogue: bias + scatter into q / k / v^T LDS tiles
        if (sec < 2) {
#pragma unroll
            for (int nj = 0; nj < 3; ++nj) {
                const int o    = obase + nj * 16 + lo;
                const float bs = qkv_b[o];
                const int oc   = o - sec * 192;
                const int hh   = oc >> 5;
                const int dd   = oc & 31;
                bf16* base = (sec == 0) ? &s_qp[hh][0] : &s_k[hh][0];
#pragma unroll
                for (int mi = 0; mi < 2; ++mi)
#pragma unroll
                    for (int r = 0; r < 4; ++r) {
                        const int n = mib * 32 + mi * 16 + hi * 4 + r;
                        const float v = acc[mi][nj][r] + bs;
                        *qk_ptr(base, n, dd) = (sec == 0) ? (bf16)(v * QK_SCALE) : (bf16)v;
                    }
            }
        } else {
            // v waves: rows n contiguous in r -> vectorized b64 stores into vt
#pragma unroll
            for (int nj = 0; nj < 3; ++nj) {
                const int o    = obase + nj * 16 + lo;
                const float bs = qkv_b[o];
                const int oc   = o - 384;
                const int hh   = oc >> 5;
                const int dd   = oc & 31;
#pragma unroll
                for (int mi = 0; mi < 2; ++mi) {
                    const int n0 = mib * 32 + mi * 16 + hi * 4;
                    bf16x4 pk;
#pragma unroll
                    for (int r = 0; r < 4; ++r) pk[r] = (bf16)(acc[mi][nj][r] + bs);
                    *(bf16x4*)vt_ptr(&s_vt[hh][0], dd, n0) = pk;
                }
            }
        }
    }
    __syncthreads();                               // barrier 2: q/k/vt visible

    // ====== Phase 2: attention, fully per-wave decoupled (no barriers) ========
    {
        const int h    = wv >> 1;    // 0..5
        const int arow = (wv & 1) * 32;
        bf16* qb    = &s_qp[h][0];
        bf16* kbase = &s_k[h][0];

        // combo loads issued first (latency hidden under LDS reads + MFMA)
        f32x4 cv[2][4];
        if (USE_COMBO) {
            const float* cb = combo + (((size_t)(b & 63) * 6 + h) << 12);
#pragma unroll
            for (int mi = 0; mi < 2; ++mi)
#pragma unroll
                for (int nt = 0; nt < 4; ++nt)
#pragma unroll
                    for (int r = 0; r < 4; ++r)
                        cv[mi][nt][r] = cb[(arow + mi * 16 + hi * 4 + r) * 64 + nt * 16 + lo];
        }

        bf16x8 qa0 = *(const bf16x8*)qk_ptr(qb, arow + lo, hi * 8);
        bf16x8 qa1 = *(const bf16x8*)qk_ptr(qb, arow + 16 + lo, hi * 8);
        bf16x8 kb0 = *(const bf16x8*)qk_ptr(kbase,  0 + lo, hi * 8);
        bf16x8 kb1 = *(const bf16x8*)qk_ptr(kbase, 16 + lo, hi * 8);
        bf16x8 kb2 = *(const bf16x8*)qk_ptr(kbase, 32 + lo, hi * 8);
        bf16x8 kb3 = *(const bf16x8*)qk_ptr(kbase, 48 + lo, hi * 8);

        f32x4 s[2][4];
#pragma unroll
        for (int mi = 0; mi < 2; ++mi)
#pragma unroll
            for (int nt = 0; nt < 4; ++nt) s[mi][nt] = (f32x4){0.f, 0.f, 0.f, 0.f};
        s[0][0] = __builtin_amdgcn_mfma_f32_16x16x32_bf16(qa0, kb0, s[0][0], 0, 0, 0);
        s[0][1] = __builtin_amdgcn_mfma_f32_16x16x32_bf16(qa0, kb1, s[0][1], 0, 0, 0);
        s[0][2] = __builtin_amdgcn_mfma_f32_16x16x32_bf16(qa0, kb2, s[0][2], 0, 0, 0);
        s[0][3] = __builtin_amdgcn_mfma_f32_16x16x32_bf16(qa0, kb3, s[0][3], 0, 0, 0);
        s[1][0] = __builtin_amdgcn_mfma_f32_16x16x32_bf16(qa1, kb0, s[1][0], 0, 0, 0);
        s[1][1] = __builtin_amdgcn_mfma_f32_16x16x32_bf16(qa1, kb1, s[1][1], 0, 0, 0);
        s[1][2] = __builtin_amdgcn_mfma_f32_16x16x32_bf16(qa1, kb2, s[1][2], 0, 0, 0);
        s[1][3] = __builtin_amdgcn_mfma_f32_16x16x32_bf16(qa1, kb3, s[1][3], 0, 0, 0);

        if (USE_COMBO) {
#pragma unroll
            for (int mi = 0; mi < 2; ++mi)
#pragma unroll
                for (int nt = 0; nt < 4; ++nt) s[mi][nt] += cv[mi][nt];
        } else {
            const float* mk = mask + (size_t)(b & 63) * 2401;
            const float* rb = rpbx + h * 2401;
#pragma unroll
            for (int nt = 0; nt < 4; ++nt) {
                const int j = nt * 16 + lo;
#pragma unroll
                for (int mi = 0; mi < 2; ++mi)
#pragma unroll
                    for (int r = 0; r < 4; ++r) {
                        const int i = arow + mi * 16 + hi * 4 + r;
                        float sv = s[mi][nt][r];
                        if (j >= 49 || i >= 49) sv = -1e30f;
                        else sv += rb[i * 49 + j] + mk[i * 49 + j];
                        s[mi][nt][r] = sv;
                    }
            }
        }

        // softmax over j (4 regs x 16 lanes sharing hi)
#pragma unroll
        for (int mi = 0; mi < 2; ++mi)
#pragma unroll
            for (int r = 0; r < 4; ++r) {
                float m = fmaxf(fmaxf(s[mi][0][r], s[mi][1][r]),
                                fmaxf(s[mi][2][r], s[mi][3][r]));
                m = fmaxf(m, __shfl_xor(m, 1));
                m = fmaxf(m, __shfl_xor(m, 2));
                m = fmaxf(m, __shfl_xor(m, 4));
                m = fmaxf(m, __shfl_xor(m, 8));
                float sum = 0.f;
#pragma unroll
                for (int nt = 0; nt < 4; ++nt) {
                    float pv = __expf(s[mi][nt][r] - m);
                    s[mi][nt][r] = pv;
                    sum += pv;
                }
                sum += __shfl_xor(sum, 1);
                sum += __shfl_xor(sum, 2);
                sum += __shfl_xor(sum, 4);
                sum += __shfl_xor(sum, 8);
                const float inv = 1.0f / sum;
#pragma unroll
                for (int nt = 0; nt < 4; ++nt) s[mi][nt][r] *= inv;
            }

        // PV: rows arow..arow+31; P staged into this pass's OWN q rows
        f32x4 o00 = (f32x4){0.f,0.f,0.f,0.f}, o01 = (f32x4){0.f,0.f,0.f,0.f};
        f32x4 o10 = (f32x4){0.f,0.f,0.f,0.f}, o11 = (f32x4){0.f,0.f,0.f,0.f};
#pragma unroll
        for (int kk = 0; kk < 2; ++kk) {
#pragma unroll
            for (int mi = 0; mi < 2; ++mi)
#pragma unroll
                for (int c = 0; c < 2; ++c) {
                    const int nt = kk * 2 + c;
#pragma unroll
                    for (int r = 0; r < 4; ++r)
                        *qk_ptr(qb, arow + mi * 16 + hi * 4 + r, c * 16 + lo) =
                            (bf16)s[mi][nt][r];
                }
            bf16x8 pa0 = *(const bf16x8*)qk_ptr(qb, arow + lo, hi * 8);
            bf16x8 pa1 = *(const bf16x8*)qk_ptr(qb, arow + 16 + lo, hi * 8);
            bf16x8 vb0 = *(const bf16x8*)vt_ptr(&s_vt[h][0],  0 + lo, kk * 32 + hi * 8);
            bf16x8 vb1 = *(const bf16x8*)vt_ptr(&s_vt[h][0], 16 + lo, kk * 32 + hi * 8);
            o00 = __builtin_amdgcn_mfma_f32_16x16x32_bf16(pa0, vb0, o00, 0, 0, 0);
            o10 = __builtin_amdgcn_mfma_f32_16x16x32_bf16(pa1, vb0, o10, 0, 0, 0);
            o01 = __builtin_amdgcn_mfma_f32_16x16x32_bf16(pa0, vb1, o01, 0, 0, 0);
            o11 = __builtin_amdgcn_mfma_f32_16x16x32_bf16(pa1, vb1, o11, 0, 0, 0);
        }

        // scatter head output into ao = s_x (dead after phase 1; no race)
#pragma unroll
        for (int r = 0; r < 4; ++r) {
            const int n0 = arow + hi * 4 + r;
            const int n1 = n0 + 16;
            *x_ptr(s_x, n0, h * 32 +  0 + lo) = (bf16)o00[r];
            *x_ptr(s_x, n0, h * 32 + 16 + lo) = (bf16)o01[r];
            *x_ptr(s_x, n1, h * 32 +  0 + lo) = (bf16)o10[r];
            *x_ptr(s_x, n1, h * 32 + 16 + lo) = (bf16)o11[r];
        }
    }
    __syncthreads();                               // barrier 3: ao visible

    // ============ Phase 3: out = ao @ out_w^T + out_b (1 col-tile per wave) ===
    {
        const int o2 = wv * 16 + lo;           // 0..191
        f32x4 facc[4];
#pragma unroll
        for (int mi = 0; mi < 4; ++mi) facc[mi] = (f32x4){0.f, 0.f, 0.f, 0.f};

        bf16x8 fbc = *(const bf16x8*)(out_wb + o2 * 192 + hi * 8);
#pragma unroll
        for (int kk = 0; kk < 6; ++kk) {
            bf16x8 fbn;
            if (kk < 5) fbn = *(const bf16x8*)(out_wb + o2 * 192 + (kk + 1) * 32 + hi * 8);
            bf16x8 fa[4];
#pragma unroll
            for (int mi = 0; mi < 4; ++mi)
                fa[mi] = *(const bf16x8*)x_ptr(s_x, mi * 16 + lo, kk * 32 + hi * 8);
#pragma unroll
            for (int mi = 0; mi < 4; ++mi)
                facc[mi] = __builtin_amdgcn_mfma_f32_16x16x32_bf16(fa[mi], fbc, facc[mi], 0, 0, 0);
            fbc = fbn;
        }

        const float ob = out_b[o2];
        float* ow = out + (size_t)b * 9408;
#pragma unroll
        for (int mi = 0; mi < 4; ++mi)
#pragma unroll
            for (int r = 0; r < 4; ++r) {
                const int n = mi * 16 + hi * 4 + r;
                if (n < 49) ow[n * 192 + o2] = facc[mi][r] + ob;
            }
    }
}

extern "C" void kernel_launch(void* const* d_in, const int* in_sizes, int n_in,
                              void* d_out, int out_size, void* d_ws, size_t ws_size,
                              hipStream_t stream) {
    const float* x      = (const float*)d_in[0];
    const float* mask   = (const float*)d_in[1];
    const float* qkv_w  = (const float*)d_in[2];
    const float* qkv_b  = (const float*)d_in[3];
    const float* out_w  = (const float*)d_in[4];
    const float* out_b  = (const float*)d_in[5];
    const float* rpb    = (const float*)d_in[6];
    float* out          = (float*)d_out;

    char* ws = (char*)d_ws;
    bf16*  qkv_wb = (bf16*)ws;                       // 110592 * 2 = 221184 B
    bf16*  out_wb = (bf16*)(ws + 221184);            //  36864 * 2 =  73728 B
    float* rpbx   = (float*)(ws + 294912);           //  14406 * 4 =  57624 B
    float* combo  = (float*)(ws + 352768);           // 1572864 * 4 = 6291456 B
    const bool use_combo = ws_size >= (size_t)(352768 + 6291456);

    hipLaunchKernelGGL(wmsa_prep, dim3(6144), dim3(256), 0, stream,
                       qkv_w, out_w, rpb, mask, qkv_wb, out_wb, rpbx, combo,
                       use_combo ? 1 : 0);
    if (use_combo)
        hipLaunchKernelGGL(HIP_KERNEL_NAME(wmsa_fused<true>), dim3(4096), dim3(768), 0, stream,
                           x, mask, qkv_b, out_b, qkv_wb, out_wb, rpbx, combo, out);
    else
        hipLaunchKernelGGL(HIP_KERNEL_NAME(wmsa_fused<false>), dim3(4096), dim3(768), 0, stream,
                           x, mask, qkv_b, out_b, qkv_wb, out_wb, rpbx, combo, out);
}

// Round 15
// 257.224 us; speedup vs baseline: 3.2789x; 1.0623x over previous
//
#include <hip/hip_runtime.h>
#include <hip/hip_bf16.h>

typedef __bf16 bf16;
typedef __bf16 bf16x4 __attribute__((ext_vector_type(4)));
typedef __bf16 bf16x8 __attribute__((ext_vector_type(8)));
typedef float f32x4 __attribute__((ext_vector_type(4)));
typedef float floatv4 __attribute__((ext_vector_type(4)));

#define QK_SCALE 0.17677669529663687f

// ---- padded affine LDS addressing (no XOR swizzle) ---------------------------
#define X_LD 200   // x/ao tile [64][200]
#define QK_LD 40   // q/k tiles [64][40]
#define VT_LD 72   // vt tiles [32][72]

__device__ __forceinline__ bf16* x_ptr(bf16* base, int row, int col) {
    return base + row * X_LD + col;
}
__device__ __forceinline__ bf16* qk_ptr(bf16* base, int row, int col) {
    return base + row * QK_LD + col;
}
__device__ __forceinline__ bf16* vt_ptr(bf16* base, int row, int col) {
    return base + row * VT_LD + col;
}

// ---------------- prep: weight bf16 convert + rpb expand + combo table --------
__global__ void wmsa_prep(const float* __restrict__ qkv_w,
                          const float* __restrict__ out_w,
                          const float* __restrict__ rpb_table,
                          const float* __restrict__ mask,
                          bf16* __restrict__ qkv_wb,
                          bf16* __restrict__ out_wb,
                          float* __restrict__ rpbx,
                          float* __restrict__ combo,
                          int build_combo) {
    int t = blockIdx.x * 256 + threadIdx.x;
    if (t < 110592) qkv_wb[t] = (bf16)qkv_w[t];
    if (t < 36864)  out_wb[t] = (bf16)out_w[t];
    if (t < 14406) {
        int h = t / 2401, ij = t % 2401, i = ij / 49, j = ij % 49;
        int ri = (i / 7 - j / 7 + 6) * 13 + (i % 7 - j % 7 + 6);
        rpbx[t] = rpb_table[ri * 6 + h];
    }
    if (build_combo && t < 64 * 6 * 64 * 64) {
        int j = t & 63, i = (t >> 6) & 63, r = t >> 12;
        int h = r % 6, w = r / 6;
        float v = -1e30f;
        if (i < 49 && j < 49) {
            int ri = (i / 7 - j / 7 + 6) * 13 + (i % 7 - j % 7 + 6);
            v = rpb_table[ri * 6 + h] + mask[w * 2401 + i * 49 + j];
        }
        combo[t] = v;
    }
}

// =================== fused kernel: one window per block, 12 waves =============
// r13/r14 structure; phase 2 uses SWAPPED mfma operands (S^T, O^T) so softmax
// is 2-shuffle and all P/ao writes are bf16x4.
template <bool USE_COMBO>
__global__ __launch_bounds__(768, 3) void wmsa_fused(
    const float* __restrict__ x, const float* __restrict__ mask,
    const float* __restrict__ qkv_b, const float* __restrict__ out_b,
    const bf16* __restrict__ qkv_wb, const bf16* __restrict__ out_wb,
    const float* __restrict__ rpbx, const float* __restrict__ combo,
    float* __restrict__ out)
{
    __shared__ __align__(16) bf16 s_x[64 * X_LD];     // x [64][200]; later ao
    __shared__ __align__(16) bf16 s_qp[6][64 * QK_LD];// q, then P (per head)
    __shared__ __align__(16) bf16 s_k[6][64 * QK_LD]; // k (per head)
    __shared__ __align__(16) bf16 s_vt[6][32 * VT_LD];// v^T

    const int b    = blockIdx.x;
    const int tid  = threadIdx.x;
    const int wv   = tid >> 6;      // 0..11
    const int lane = tid & 63;
    const int lo   = lane & 15;
    const int hi   = lane >> 4;     // 0..3

    const float* xw    = x + (size_t)b * 9408;
    const int    obase = wv * 48;   // 48 qkv output cols per wave
    const int    sec   = wv >> 2;   // 0=q 1=k 2=v (uniform per wave)

    // ============ Phase 0: stage x (fp32 -> bf16) into LDS, zero-padded =======
    {
        const int c0 = tid;                       // rows 0..31
        const int r0s = c0 / 24, cc0 = c0 % 24;
        const float* p0 = xw + r0s * 192 + cc0 * 8;
        floatv4 f0 = *(const floatv4*)p0;
        floatv4 f1 = *(const floatv4*)(p0 + 4);
        bf16x8 v;
        v[0]=(bf16)f0[0]; v[1]=(bf16)f0[1]; v[2]=(bf16)f0[2]; v[3]=(bf16)f0[3];
        v[4]=(bf16)f1[0]; v[5]=(bf16)f1[1]; v[6]=(bf16)f1[2]; v[7]=(bf16)f1[3];
        *(bf16x8*)&s_x[r0s * X_LD + cc0 * 8] = v;

        const int c1 = tid + 768;                 // rows 32..63 (zero >= 49)
        const int r1s = c1 / 24, cc1 = c1 % 24;
        bf16x8 w = {};
        if (r1s < 49) {
            const float* p1 = xw + r1s * 192 + cc1 * 8;
            floatv4 g0 = *(const floatv4*)p1;
            floatv4 g1 = *(const floatv4*)(p1 + 4);
            w[0]=(bf16)g0[0]; w[1]=(bf16)g0[1]; w[2]=(bf16)g0[2]; w[3]=(bf16)g0[3];
            w[4]=(bf16)g1[0]; w[5]=(bf16)g1[1]; w[6]=(bf16)g1[2]; w[7]=(bf16)g1[3];
        }
        *(bf16x8*)&s_x[r1s * X_LD + cc1 * 8] = w;
    }
    __syncthreads();                               // barrier 1: x visible

    // ============ Phase 1: QKV = x @ qkv_w^T + qkv_b (A from LDS, B 2-deep) ===
#pragma unroll 1
    for (int mib = 0; mib < 2; ++mib) {
        f32x4 acc[2][3];
#pragma unroll
        for (int mi = 0; mi < 2; ++mi)
#pragma unroll
            for (int nj = 0; nj < 3; ++nj) acc[mi][nj] = (f32x4){0.f, 0.f, 0.f, 0.f};

        const int r0 = mib * 32 + lo;
        const int r1 = r0 + 16;        // rows >= 49 are zeros in s_x

        auto loadB = [&](bf16x8* dst, int kk) {
#pragma unroll
            for (int nj = 0; nj < 3; ++nj)
                dst[nj] = *(const bf16x8*)(qkv_wb + (obase + nj * 16 + lo) * 192 + kk * 32 + hi * 8);
        };

        bf16x8 b0_[3], b1_[3], b2_[3];
        loadB(b0_, 0);
        loadB(b1_, 1);
#pragma unroll
        for (int kk = 0; kk < 6; ++kk) {
            if (kk < 4) loadB(b2_, kk + 2);
            bf16x8 a0 = *(const bf16x8*)x_ptr(s_x, r0, kk * 32 + hi * 8);
            bf16x8 a1 = *(const bf16x8*)x_ptr(s_x, r1, kk * 32 + hi * 8);
            acc[0][0] = __builtin_amdgcn_mfma_f32_16x16x32_bf16(a0, b0_[0], acc[0][0], 0, 0, 0);
            acc[1][0] = __builtin_amdgcn_mfma_f32_16x16x32_bf16(a1, b0_[0], acc[1][0], 0, 0, 0);
            acc[0][1] = __builtin_amdgcn_mfma_f32_16x16x32_bf16(a0, b0_[1], acc[0][1], 0, 0, 0);
            acc[1][1] = __builtin_amdgcn_mfma_f32_16x16x32_bf16(a1, b0_[1], acc[1][1], 0, 0, 0);
            acc[0][2] = __builtin_amdgcn_mfma_f32_16x16x32_bf16(a0, b0_[2], acc[0][2], 0, 0, 0);
            acc[1][2] = __builtin_amdgcn_mfma_f32_16x16x32_bf16(a1, b0_[2], acc[1][2], 0, 0, 0);
            b0_[0] = b1_[0]; b0_[1] = b1_[1]; b0_[2] = b1_[2];
            b1_[0] = b2_[0]; b1_[1] = b2_[1]; b1_[2] = b2_[2];
        }

        // epilogue: bias + scatter into q / k / v^T LDS tiles
        if (sec < 2) {
#pragma unroll
            for (int nj = 0; nj < 3; ++nj) {
                const int o    = obase + nj * 16 + lo;
                const float bs = qkv_b[o];
                const int oc   = o - sec * 192;
                const int hh   = oc >> 5;
                const int dd   = oc & 31;
                bf16* base = (sec == 0) ? &s_qp[hh][0] : &s_k[hh][0];
#pragma unroll
                for (int mi = 0; mi < 2; ++mi)
#pragma unroll
                    for (int r = 0; r < 4; ++r) {
                        const int n = mib * 32 + mi * 16 + hi * 4 + r;
                        const float v = acc[mi][nj][r] + bs;
                        *qk_ptr(base, n, dd) = (sec == 0) ? (bf16)(v * QK_SCALE) : (bf16)v;
                    }
            }
        } else {
            // v waves: rows n contiguous in r -> vectorized b64 stores into vt
#pragma unroll
            for (int nj = 0; nj < 3; ++nj) {
                const int o    = obase + nj * 16 + lo;
                const float bs = qkv_b[o];
                const int oc   = o - 384;
                const int hh   = oc >> 5;
                const int dd   = oc & 31;
#pragma unroll
                for (int mi = 0; mi < 2; ++mi) {
                    const int n0 = mib * 32 + mi * 16 + hi * 4;
                    bf16x4 pk;
#pragma unroll
                    for (int r = 0; r < 4; ++r) pk[r] = (bf16)(acc[mi][nj][r] + bs);
                    *(bf16x4*)vt_ptr(&s_vt[hh][0], dd, n0) = pk;
                }
            }
        }
    }
    __syncthreads();                               // barrier 2: q/k/vt visible

    // ====== Phase 2: attention, swapped operands, per-wave decoupled ==========
    {
        const int h    = wv >> 1;    // 0..5
        const int arow = (wv & 1) * 32;
        bf16* qb    = &s_qp[h][0];
        bf16* kbase = &s_k[h][0];

        // combo loads: lane owns col i = arow+mi*16+lo, rows j = nt*16+hi*4+..+3
        // -> one floatv4 per (mi,nt): 8 dwordx4 instead of 32 dword
        f32x4 cv[2][4];
        if (USE_COMBO) {
            const float* cb = combo + (((size_t)(b & 63) * 6 + h) << 12);
#pragma unroll
            for (int mi = 0; mi < 2; ++mi) {
                const int i = arow + mi * 16 + lo;
#pragma unroll
                for (int nt = 0; nt < 4; ++nt)
                    cv[mi][nt] = *(const floatv4*)(cb + i * 64 + nt * 16 + hi * 4);
            }
        }

        bf16x8 qa0 = *(const bf16x8*)qk_ptr(qb, arow + lo, hi * 8);
        bf16x8 qa1 = *(const bf16x8*)qk_ptr(qb, arow + 16 + lo, hi * 8);
        bf16x8 kb0 = *(const bf16x8*)qk_ptr(kbase,  0 + lo, hi * 8);
        bf16x8 kb1 = *(const bf16x8*)qk_ptr(kbase, 16 + lo, hi * 8);
        bf16x8 kb2 = *(const bf16x8*)qk_ptr(kbase, 32 + lo, hi * 8);
        bf16x8 kb3 = *(const bf16x8*)qk_ptr(kbase, 48 + lo, hi * 8);

        // S^T = mfma(K, Q): t[nt][mi], col i = arow+mi*16+lo, row j = nt*16+hi*4+r
        f32x4 t[4][2];
#pragma unroll
        for (int nt = 0; nt < 4; ++nt)
#pragma unroll
            for (int mi = 0; mi < 2; ++mi) t[nt][mi] = (f32x4){0.f, 0.f, 0.f, 0.f};
        t[0][0] = __builtin_amdgcn_mfma_f32_16x16x32_bf16(kb0, qa0, t[0][0], 0, 0, 0);
        t[1][0] = __builtin_amdgcn_mfma_f32_16x16x32_bf16(kb1, qa0, t[1][0], 0, 0, 0);
        t[2][0] = __builtin_amdgcn_mfma_f32_16x16x32_bf16(kb2, qa0, t[2][0], 0, 0, 0);
        t[3][0] = __builtin_amdgcn_mfma_f32_16x16x32_bf16(kb3, qa0, t[3][0], 0, 0, 0);
        t[0][1] = __builtin_amdgcn_mfma_f32_16x16x32_bf16(kb0, qa1, t[0][1], 0, 0, 0);
        t[1][1] = __builtin_amdgcn_mfma_f32_16x16x32_bf16(kb1, qa1, t[1][1], 0, 0, 0);
        t[2][1] = __builtin_amdgcn_mfma_f32_16x16x32_bf16(kb2, qa1, t[2][1], 0, 0, 0);
        t[3][1] = __builtin_amdgcn_mfma_f32_16x16x32_bf16(kb3, qa1, t[3][1], 0, 0, 0);

        if (USE_COMBO) {
#pragma unroll
            for (int mi = 0; mi < 2; ++mi)
#pragma unroll
                for (int nt = 0; nt < 4; ++nt) t[nt][mi] += cv[mi][nt];
        } else {
            const float* mk = mask + (size_t)(b & 63) * 2401;
            const float* rb = rpbx + h * 2401;
#pragma unroll
            for (int nt = 0; nt < 4; ++nt)
#pragma unroll
                for (int mi = 0; mi < 2; ++mi)
#pragma unroll
                    for (int r = 0; r < 4; ++r) {
                        const int i = arow + mi * 16 + lo;       // query
                        const int j = nt * 16 + hi * 4 + r;      // key
                        float sv = t[nt][mi][r];
                        if (j >= 49 || i >= 49) sv = -1e30f;
                        else sv += rb[i * 49 + j] + mk[i * 49 + j];
                        t[nt][mi][r] = sv;
                    }
        }

        // softmax over j: 16 values in-lane + reduce across the 4 hi-groups
#pragma unroll
        for (int mi = 0; mi < 2; ++mi) {
            float m = t[0][mi][0];
#pragma unroll
            for (int nt = 0; nt < 4; ++nt)
#pragma unroll
                for (int r = 0; r < 4; ++r) m = fmaxf(m, t[nt][mi][r]);
            m = fmaxf(m, __shfl_xor(m, 16));
            m = fmaxf(m, __shfl_xor(m, 32));
            float sum = 0.f;
#pragma unroll
            for (int nt = 0; nt < 4; ++nt)
#pragma unroll
                for (int r = 0; r < 4; ++r) {
                    float pv = __expf(t[nt][mi][r] - m);
                    t[nt][mi][r] = pv;
                    sum += pv;
                }
            sum += __shfl_xor(sum, 16);
            sum += __shfl_xor(sum, 32);
            const float inv = 1.0f / sum;
#pragma unroll
            for (int nt = 0; nt < 4; ++nt)
#pragma unroll
                for (int r = 0; r < 4; ++r) t[nt][mi][r] *= inv;
        }

        // PV swapped: O^T = mfma(V^T, P): o[nd][mq], col i = arow+mq*16+lo,
        // row d = nd*16+hi*4+r. P staged per 32-col chunk with bf16x4 stores.
        f32x4 o00 = (f32x4){0.f,0.f,0.f,0.f}, o01 = (f32x4){0.f,0.f,0.f,0.f};
        f32x4 o10 = (f32x4){0.f,0.f,0.f,0.f}, o11 = (f32x4){0.f,0.f,0.f,0.f};
#pragma unroll
        for (int kk = 0; kk < 2; ++kk) {
#pragma unroll
            for (int mi = 0; mi < 2; ++mi)
#pragma unroll
                for (int c = 0; c < 2; ++c) {
                    const int nt = kk * 2 + c;
                    bf16x4 pk;
#pragma unroll
                    for (int r = 0; r < 4; ++r) pk[r] = (bf16)t[nt][mi][r];
                    *(bf16x4*)qk_ptr(qb, arow + mi * 16 + lo, c * 16 + hi * 4) = pk;
                }
            bf16x8 pa0 = *(const bf16x8*)qk_ptr(qb, arow + lo, hi * 8);
            bf16x8 pa1 = *(const bf16x8*)qk_ptr(qb, arow + 16 + lo, hi * 8);
            bf16x8 vb0 = *(const bf16x8*)vt_ptr(&s_vt[h][0],  0 + lo, kk * 32 + hi * 8);
            bf16x8 vb1 = *(const bf16x8*)vt_ptr(&s_vt[h][0], 16 + lo, kk * 32 + hi * 8);
            o00 = __builtin_amdgcn_mfma_f32_16x16x32_bf16(vb0, pa0, o00, 0, 0, 0);
            o01 = __builtin_amdgcn_mfma_f32_16x16x32_bf16(vb0, pa1, o01, 0, 0, 0);
            o10 = __builtin_amdgcn_mfma_f32_16x16x32_bf16(vb1, pa0, o10, 0, 0, 0);
            o11 = __builtin_amdgcn_mfma_f32_16x16x32_bf16(vb1, pa1, o11, 0, 0, 0);
        }

        // ao writes: lane holds 4 consecutive d -> bf16x4 stores into s_x (dead)
        {
            bf16x4 w00, w01, w10, w11;
#pragma unroll
            for (int r = 0; r < 4; ++r) {
                w00[r] = (bf16)o00[r]; w01[r] = (bf16)o01[r];
                w10[r] = (bf16)o10[r]; w11[r] = (bf16)o11[r];
            }
            *(bf16x4*)x_ptr(s_x, arow +  0 + lo, h * 32 +  0 + hi * 4) = w00;
            *(bf16x4*)x_ptr(s_x, arow + 16 + lo, h * 32 +  0 + hi * 4) = w01;
            *(bf16x4*)x_ptr(s_x, arow +  0 + lo, h * 32 + 16 + hi * 4) = w10;
            *(bf16x4*)x_ptr(s_x, arow + 16 + lo, h * 32 + 16 + hi * 4) = w11;
        }
    }
    __syncthreads();                               // barrier 3: ao visible

    // ============ Phase 3: out = ao @ out_w^T + out_b (1 col-tile per wave) ===
    {
        const int o2 = wv * 16 + lo;           // 0..191
        f32x4 facc[4];
#pragma unroll
        for (int mi = 0; mi < 4; ++mi) facc[mi] = (f32x4){0.f, 0.f, 0.f, 0.f};

        bf16x8 fbc = *(const bf16x8*)(out_wb + o2 * 192 + hi * 8);
#pragma unroll
        for (int kk = 0; kk < 6; ++kk) {
            bf16x8 fbn;
            if (kk < 5) fbn = *(const bf16x8*)(out_wb + o2 * 192 + (kk + 1) * 32 + hi * 8);
            bf16x8 fa[4];
#pragma unroll
            for (int mi = 0; mi < 4; ++mi)
                fa[mi] = *(const bf16x8*)x_ptr(s_x, mi * 16 + lo, kk * 32 + hi * 8);
#pragma unroll
            for (int mi = 0; mi < 4; ++mi)
                facc[mi] = __builtin_amdgcn_mfma_f32_16x16x32_bf16(fa[mi], fbc, facc[mi], 0, 0, 0);
            fbc = fbn;
        }

        const float ob = out_b[o2];
        float* ow = out + (size_t)b * 9408;
#pragma unroll
        for (int mi = 0; mi < 4; ++mi)
#pragma unroll
            for (int r = 0; r < 4; ++r) {
                const int n = mi * 16 + hi * 4 + r;
                if (n < 49) ow[n * 192 + o2] = facc[mi][r] + ob;
            }
    }
}

extern "C" void kernel_launch(void* const* d_in, const int* in_sizes, int n_in,
                              void* d_out, int out_size, void* d_ws, size_t ws_size,
                              hipStream_t stream) {
    const float* x      = (const float*)d_in[0];
    const float* mask   = (const float*)d_in[1];
    const float* qkv_w  = (const float*)d_in[2];
    const float* qkv_b  = (const float*)d_in[3];
    const float* out_w  = (const float*)d_in[4];
    const float* out_b  = (const float*)d_in[5];
    const float* rpb    = (const float*)d_in[6];
    float* out          = (float*)d_out;

    char* ws = (char*)d_ws;
    bf16*  qkv_wb = (bf16*)ws;                       // 110592 * 2 = 221184 B
    bf16*  out_wb = (bf16*)(ws + 221184);            //  36864 * 2 =  73728 B
    float* rpbx   = (float*)(ws + 294912);           //  14406 * 4 =  57624 B
    float* combo  = (float*)(ws + 352768);           // 1572864 * 4 = 6291456 B
    const bool use_combo = ws_size >= (size_t)(352768 + 6291456);

    hipLaunchKernelGGL(wmsa_prep, dim3(6144), dim3(256), 0, stream,
                       qkv_w, out_w, rpb, mask, qkv_wb, out_wb, rpbx, combo,
                       use_combo ? 1 : 0);
    if (use_combo)
        hipLaunchKernelGGL(HIP_KERNEL_NAME(wmsa_fused<true>), dim3(4096), dim3(768), 0, stream,
                           x, mask, qkv_b, out_b, qkv_wb, out_wb, rpbx, combo, out);
    else
        hipLaunchKernelGGL(HIP_KERNEL_NAME(wmsa_fused<false>), dim3(4096), dim3(768), 0, stream,
                           x, mask, qkv_b, out_b, qkv_wb, out_wb, rpbx, combo, out);
}